// Round 3
// baseline (726.292 us; speedup 1.0000x reference)
//
#include <hip/hip_runtime.h>
#include <hip/hip_bf16.h>

typedef short bf16x8 __attribute__((ext_vector_type(8)));
typedef float f32x4 __attribute__((ext_vector_type(4)));
typedef unsigned short us4v __attribute__((ext_vector_type(4)));

#define DEV static __device__ __forceinline__

DEV float bf2f(unsigned short u){ unsigned int x = ((unsigned int)u)<<16; float f; __builtin_memcpy(&f,&x,4); return f; }
DEV unsigned short f2bf(float f){ unsigned int x; __builtin_memcpy(&x,&f,4); x = (x + 0x7fffu + ((x>>16)&1u)) >> 16; return (unsigned short)x; }
DEV unsigned int pack_bf16x2(float lo, float hi){
  __hip_bfloat162 h = __float22bfloat162_rn(float2{lo, hi});
  unsigned int u; __builtin_memcpy(&u, &h, 4); return u;
}

DEV void stor(unsigned short* p, float v){ *p = f2bf(v); }
DEV void stor(float* p, float v){ *p = v; }

#define GLOAD_LDS16(gptr, lptr) \
  __builtin_amdgcn_global_load_lds((__attribute__((address_space(1))) void*)(gptr), \
      (__attribute__((address_space(3))) void*)(lptr), 16, 0, 0)

// C = A[M,K] @ Bt[N,K]^T, bf16 inputs, OutT output. 128x128 tile, BK=32, 4 waves.
template<typename OutT>
__global__ __launch_bounds__(256) void gemm_bt(
    const unsigned short* __restrict__ A,
    const unsigned short* __restrict__ Bt,
    OutT* __restrict__ C, int M, int N, int K)
{
  __shared__ unsigned short As[128*32];
  __shared__ unsigned short Bs[128*32];
  const int tid = threadIdx.x;
  const int w = tid>>6, l = tid&63, g = l>>4, q = l&15;
  const int m0 = blockIdx.x*128, n0 = blockIdx.y*128;
  f32x4 acc[4][4];
  const f32x4 fz = {0.f,0.f,0.f,0.f};
  for (int i=0;i<4;i++) for(int j=0;j<4;j++) acc[i][j] = fz;
  for (int k0 = 0; k0 < K; k0 += 32) {
    __syncthreads();
    #pragma unroll
    for (int r = 0; r < 2; ++r) {
      int p = r*4096 + tid*16;
      int row = p>>6, colb = p&63;
      const char* ga = (const char*)(A  + (size_t)(m0+row)*K + k0) + colb;
      const char* gb = (const char*)(Bt + (size_t)(n0+row)*K + k0) + colb;
      GLOAD_LDS16(ga, (char*)As + r*4096 + w*1024);
      GLOAD_LDS16(gb, (char*)Bs + r*4096 + w*1024);
    }
    __syncthreads();
    bf16x8 af[4], bfr[4];
    #pragma unroll
    for (int i=0;i<4;i++){
      af[i]  = *(const bf16x8*)&As[((w>>1)*64 + i*16 + q)*32 + g*8];
      bfr[i] = *(const bf16x8*)&Bs[((w&1)*64 + i*16 + q)*32 + g*8];
    }
    #pragma unroll
    for (int i=0;i<4;i++)
      #pragma unroll
      for (int j=0;j<4;j++)
        acc[i][j] = __builtin_amdgcn_mfma_f32_16x16x32_bf16(af[i], bfr[j], acc[i][j], 0,0,0);
  }
  #pragma unroll
  for (int i=0;i<4;i++)
    #pragma unroll
    for (int j=0;j<4;j++)
      #pragma unroll
      for (int v=0;v<4;v++){
        int row = m0 + (w>>1)*64 + i*16 + g*4 + v;
        int col = n0 + (w&1)*64 + j*16 + q;
        stor(&C[(size_t)row*N + col], acc[i][j][v]);
      }
}

// Differential flash attention v3.
// 4 waves as 2(wq: 32 q-rows) x 2(wk: 16-key chunk). KT=32 keys/tile, 64 tiles,
// double-buffered K/V staged via global_load_lds (pre-swizzled source),
// single __syncthreads per tile (T3 2-phase). Static-max dual softmax;
// cross-wk partial-acc combine in epilogue.
__global__ __launch_bounds__(256,3) void diff_attn(
    const unsigned short* __restrict__ Q,
    const unsigned short* __restrict__ K,
    const unsigned short* __restrict__ Vt,
    const float* __restrict__ lambp,
    unsigned short* __restrict__ aout)
{
  __shared__ unsigned short Ks0[32*128];  // 8 KiB  [key][128d], 16B-granule ^ (key&7)
  __shared__ unsigned short Ks1[32*128];  // 8 KiB
  __shared__ unsigned short Vs0[64*32];   // 4 KiB  [d][32keys], 16B-granule ^ (d&3)
  __shared__ unsigned short Vs1[64*32];   // 4 KiB
  __shared__ unsigned int  P12[4][512];   // 8 KiB  per-wave packed p1|p2
  __shared__ float         sx[256];       // 1 KiB  cross-wk denom exchange
  __shared__ f32x4         raccv[2*64*8]; // 16 KiB cross-wk acc exchange

  const int tid = threadIdx.x, w = tid>>6, l = tid&63, g = l>>4, q = l&15;
  const int wq = w>>1, wk = w&1;
  const int qblk = blockIdx.x, h = blockIdx.y, b = blockIdx.z;
  const int b2048 = b*2048;
  const int qrow0 = b2048 + qblk*64 + wq*32;
  const f32x4 fz = {0.f,0.f,0.f,0.f};

  // Q fragments (2 q-blocks x 2 ksteps x 2 subspaces), scaled by 1/8
  bf16x8 q1f[2][2], q2f[2][2];
  #pragma unroll
  for (int qb=0; qb<2; ++qb){
    const unsigned short* qp = Q + (size_t)(qrow0 + qb*16 + q)*2048 + h*128;
    #pragma unroll
    for (int ks=0; ks<2; ++ks){
      bf16x8 t1 = *(const bf16x8*)(qp + ks*32 + g*8);
      bf16x8 t2 = *(const bf16x8*)(qp + 64 + ks*32 + g*8);
      #pragma unroll
      for (int e=0;e<8;e++){
        t1[e] = (short)f2bf(bf2f((unsigned short)t1[e]) * 0.125f);
        t2[e] = (short)f2bf(bf2f((unsigned short)t2[e]) * 0.125f);
      }
      q1f[qb][ks]=t1; q2f[qb][ks]=t2;
    }
  }

  float s1p[2][4], s2p[2][4];
  f32x4 acc1[2][4], acc2[2][4];
  #pragma unroll
  for (int qb=0;qb<2;qb++)
    #pragma unroll
    for (int i=0;i<4;i++){ s1p[qb][i]=0.f; s2p[qb][i]=0.f; }
  #pragma unroll
  for (int qb=0;qb<2;qb++)
    #pragma unroll
    for (int fd=0;fd<4;fd++){ acc1[qb][fd]=fz; acc2[qb][fd]=fz; }

  auto STAGE = [&](unsigned short* K_, unsigned short* V_, int kt){
    int ktc = kt & 2047;   // clamp final wasted prefetch to valid memory
    #pragma unroll
    for (int ii=0; ii<2; ++ii){
      int krow = w*8 + ii*4 + (l>>4);
      int kgr  = (l&15) ^ (krow&7);
      const unsigned short* src = K + (size_t)(b2048 + ktc + krow)*2048 + h*128 + kgr*8;
      GLOAD_LDS16(src, (char*)K_ + (w*8+ii*4)*256);
    }
    int vrow = w*16 + (l>>2);
    int vgr  = (l&3) ^ (vrow&3);
    const unsigned short* srcv = Vt + (size_t)(h*64 + vrow)*4096 + b2048 + ktc + vgr*8;
    GLOAD_LDS16(srcv, (char*)V_ + w*1024);
  };

  auto COMPUTE = [&](const unsigned short* K_, const unsigned short* V_){
    const int sw = q&7;
    const char* kbase = (const char*)K_ + (wk*16 + q)*256;
    bf16x8 kb[2], kc[2];
    #pragma unroll
    for (int ks=0; ks<2; ++ks){
      kb[ks] = *(const bf16x8*)(kbase + (((ks*4+g)^sw)<<4));
      kc[ks] = *(const bf16x8*)(kbase + ((((2+ks)*4+g)^sw)<<4));
    }
    f32x4 z1[2], z2[2];
    #pragma unroll
    for (int qb=0; qb<2; ++qb){
      f32x4 a = fz, c2 = fz;
      a  = __builtin_amdgcn_mfma_f32_16x16x32_bf16(q1f[qb][0], kb[0], a, 0,0,0);
      a  = __builtin_amdgcn_mfma_f32_16x16x32_bf16(q1f[qb][1], kb[1], a, 0,0,0);
      c2 = __builtin_amdgcn_mfma_f32_16x16x32_bf16(q2f[qb][0], kc[0], c2, 0,0,0);
      c2 = __builtin_amdgcn_mfma_f32_16x16x32_bf16(q2f[qb][1], kc[1], c2, 0,0,0);
      z1[qb]=a; z2[qb]=c2;
    }
    unsigned int* Pw = P12[w];
    #pragma unroll
    for (int qb=0; qb<2; ++qb)
      #pragma unroll
      for (int i=0;i<4;i++){
        float p1 = __expf(z1[qb][i]), p2 = __expf(z2[qb][i]);
        unsigned int pk = pack_bf16x2(p1,p2);
        int idx = ((qb*4+i)*4+g)*16 + (((q>>2)^i)<<2) + (q&3);
        Pw[idx] = pk;
        s1p[qb][i] += bf2f((unsigned short)pk);
        s2p[qb][i] += bf2f((unsigned short)(pk>>16));
      }
    bf16x8 pa1[2], pa2[2], vb[4];
    if (g < 2){
      #pragma unroll
      for (int qb=0; qb<2; ++qb){
        int Bq = (qb*4 + (q&3))*4 + (q>>2);
        int ir = q&3;
        uint4 a0 = *(const uint4*)&Pw[(Bq*4 + ((2*g)^ir))*4];
        uint4 a1 = *(const uint4*)&Pw[(Bq*4 + ((2*g+1)^ir))*4];
        unsigned int* u1 = (unsigned int*)&pa1[qb];
        unsigned int* u2 = (unsigned int*)&pa2[qb];
        u1[0] = (a0.x & 0xffffu) | (a0.y<<16);
        u2[0] = (a0.x >> 16)     | (a0.y & 0xffff0000u);
        u1[1] = (a0.z & 0xffffu) | (a0.w<<16);
        u2[1] = (a0.z >> 16)     | (a0.w & 0xffff0000u);
        u1[2] = (a1.x & 0xffffu) | (a1.y<<16);
        u2[2] = (a1.x >> 16)     | (a1.y & 0xffff0000u);
        u1[3] = (a1.z & 0xffffu) | (a1.w<<16);
        u2[3] = (a1.z >> 16)     | (a1.w & 0xffff0000u);
      }
      const char* vbase = (const char*)V_;
      #pragma unroll
      for (int fd=0; fd<4; ++fd){
        int d = fd*16 + q;
        vb[fd] = *(const bf16x8*)(vbase + d*64 + ((((wk*2+g)^(q&3)))<<4));
      }
    } else {
      bf16x8 zz = {};
      #pragma unroll
      for (int qb=0;qb<2;qb++){ pa1[qb]=zz; pa2[qb]=zz; }
      #pragma unroll
      for (int fd=0;fd<4;fd++) vb[fd]=zz;
    }
    #pragma unroll
    for (int qb=0; qb<2; ++qb)
      #pragma unroll
      for (int fd=0; fd<4; ++fd){
        acc1[qb][fd] = __builtin_amdgcn_mfma_f32_16x16x32_bf16(pa1[qb], vb[fd], acc1[qb][fd], 0,0,0);
        acc2[qb][fd] = __builtin_amdgcn_mfma_f32_16x16x32_bf16(pa2[qb], vb[fd], acc2[qb][fd], 0,0,0);
      }
  };

  STAGE(Ks0, Vs0, 0);
  __syncthreads();
  for (int t=0; t<64; t+=2){
    STAGE(Ks1, Vs1, (t+1)*32);
    COMPUTE(Ks0, Vs0);
    __syncthreads();
    STAGE(Ks0, Vs0, (t+2)*32);
    COMPUTE(Ks1, Vs1);
    __syncthreads();
  }

  // row-sum reduce over the 16 key-lanes of each group
  #pragma unroll
  for (int qb=0;qb<2;qb++)
    #pragma unroll
    for (int i=0;i<4;i++){
      #pragma unroll
      for (int o=1;o<16;o<<=1){
        s1p[qb][i] += __shfl_xor(s1p[qb][i],o);
        s2p[qb][i] += __shfl_xor(s2p[qb][i],o);
      }
    }
  if (q==0){
    #pragma unroll
    for (int qb=0;qb<2;qb++)
      #pragma unroll
      for (int i=0;i<4;i++){
        sx[wk*128 + wq*64 + qb*16 + g*4 + i]      = s1p[qb][i];
        sx[wk*128 + wq*64 + 32 + qb*16 + g*4 + i] = s2p[qb][i];
      }
  }
  __syncthreads();
  float lamb = lambp[0];
  f32x4 r[2][4];
  #pragma unroll
  for (int qb=0;qb<2;qb++)
    #pragma unroll
    for (int i=0;i<4;i++){
      float s1t = s1p[qb][i] + sx[(wk^1)*128 + wq*64 + qb*16 + g*4 + i];
      float s2t = s2p[qb][i] + sx[(wk^1)*128 + wq*64 + 32 + qb*16 + g*4 + i];
      float in1 = 1.0f/s1t, in2 = lamb/s2t;
      #pragma unroll
      for (int fd=0; fd<4; ++fd)
        r[qb][fd][i] = acc1[qb][fd][i]*in1 - acc2[qb][fd][i]*in2;
    }
  if (wk==1){
    #pragma unroll
    for (int qb=0;qb<2;qb++)
      #pragma unroll
      for (int fd=0;fd<4;fd++)
        raccv[(wq*64 + l)*8 + qb*4+fd] = r[qb][fd];
  }
  __syncthreads();
  if (wk==0){
    #pragma unroll
    for (int qb=0;qb<2;qb++)
      #pragma unroll
      for (int fd=0;fd<4;fd++){
        f32x4 p = raccv[(wq*64 + l)*8 + qb*4+fd];
        #pragma unroll
        for (int i=0;i<4;i++){
          int row = qrow0 + qb*16 + g*4 + i;
          int col = h*64 + fd*16 + q;
          aout[(size_t)row*1024 + col] = f2bf(r[qb][fd][i] + p[i]);
        }
      }
  }
}

__global__ __launch_bounds__(256) void f32_to_bf16_k(const float* __restrict__ in, unsigned short* __restrict__ out, int n){
  int i = (blockIdx.x*256 + threadIdx.x)*4;
  if (i >= n) return;
  float4 vv = *(const float4*)(in + i);
  us4v o; o[0]=f2bf(vv.x); o[1]=f2bf(vv.y); o[2]=f2bf(vv.z); o[3]=f2bf(vv.w);
  *(us4v*)(out + i) = o;
}

// in: [R][C] f32 -> out: [C][R] bf16
__global__ void transpose_f32_bf16(const float* __restrict__ in, unsigned short* __restrict__ out, int R, int C){
  __shared__ unsigned short t[32][33];
  int c0 = blockIdx.x*32, r0 = blockIdx.y*32;
  int x = threadIdx.x, y = threadIdx.y;
  #pragma unroll
  for (int d=0; d<32; d+=8) t[y+d][x] = f2bf(in[(size_t)(r0+y+d)*C + c0 + x]);
  __syncthreads();
  #pragma unroll
  for (int d=0; d<32; d+=8) out[(size_t)(c0+y+d)*R + r0 + x] = t[x][y+d];
}

// in: [R][C] bf16 -> out: [C][R] bf16
__global__ void transpose_bf16(const unsigned short* __restrict__ in, unsigned short* __restrict__ out, int R, int C){
  __shared__ unsigned short t[32][33];
  int c0 = blockIdx.x*32, r0 = blockIdx.y*32;
  int x = threadIdx.x, y = threadIdx.y;
  #pragma unroll
  for (int d=0; d<32; d+=8) t[y+d][x] = in[(size_t)(r0+y+d)*C + c0 + x];
  __syncthreads();
  #pragma unroll
  for (int d=0; d<32; d+=8) out[(size_t)(c0+y+d)*R + r0 + x] = t[x][y+d];
}

__global__ void lamb_k(const float* lq1, const float* lk1, const float* lq2, const float* lk2, float* out){
  int i = threadIdx.x;
  float a = lq1[i]*lk1[i], c = lq2[i]*lk2[i];
  #pragma unroll
  for (int o=32;o>0;o>>=1){ a += __shfl_down(a,o); c += __shfl_down(c,o); }
  if (i==0) out[0] = expf(a) - expf(c) + 0.7778700995592560f; // LAMBDA_INIT for layer 12
}

__global__ __launch_bounds__(256) void ln_k(const float* __restrict__ in, const float* __restrict__ gam,
                                            const float* __restrict__ bet, float* __restrict__ out){
  int row = blockIdx.x, t = threadIdx.x;
  const float4* rp = (const float4*)(in + (size_t)row*1024);
  float4 v4 = rp[t];
  float s = v4.x+v4.y+v4.z+v4.w;
  float ss = v4.x*v4.x+v4.y*v4.y+v4.z*v4.z+v4.w*v4.w;
  #pragma unroll
  for (int o=1;o<64;o<<=1){ s += __shfl_xor(s,o); ss += __shfl_xor(ss,o); }
  __shared__ float red[8];
  int w = t>>6, l = t&63;
  if (l==0){ red[w]=s; red[4+w]=ss; }
  __syncthreads();
  s = red[0]+red[1]+red[2]+red[3];
  ss = red[4]+red[5]+red[6]+red[7];
  float mean = s*(1.0f/1024.0f);
  float var = ss*(1.0f/1024.0f) - mean*mean;
  float rstd = rsqrtf(var + 1e-5f);
  float4 gv = ((const float4*)gam)[t], bv = ((const float4*)bet)[t];
  float4 o;
  o.x = (v4.x-mean)*rstd*gv.x + bv.x;
  o.y = (v4.y-mean)*rstd*gv.y + bv.y;
  o.z = (v4.z-mean)*rstd*gv.z + bv.z;
  o.w = (v4.w-mean)*rstd*gv.w + bv.w;
  ((float4*)(out + (size_t)row*1024))[t] = o;
}

extern "C" void kernel_launch(void* const* d_in, const int* in_sizes, int n_in,
                              void* d_out, int out_size, void* d_ws, size_t ws_size,
                              hipStream_t stream) {
  const float* x     = (const float*)d_in[0];
  const float* Wq    = (const float*)d_in[1];
  const float* Wk    = (const float*)d_in[2];
  const float* Wv    = (const float*)d_in[3];
  const float* Wo    = (const float*)d_in[4];
  const float* lq1   = (const float*)d_in[5];
  const float* lk1   = (const float*)d_in[6];
  const float* lq2   = (const float*)d_in[7];
  const float* lk2   = (const float*)d_in[8];
  const float* gamma = (const float*)d_in[9];
  const float* beta  = (const float*)d_in[10];
  float* out = (float*)d_out;

  char* ws = (char*)d_ws;
  unsigned short* xb   = (unsigned short*)(ws);                    //  8,388,608 B
  unsigned short* WqT  = (unsigned short*)(ws + 8388608);          //  4,194,304
  unsigned short* WkT  = (unsigned short*)(ws + 12582912);         //  4,194,304
  unsigned short* WvT  = (unsigned short*)(ws + 16777216);         //  2,097,152
  unsigned short* WoT  = (unsigned short*)(ws + 18874368);         //  2,097,152
  unsigned short* Qb   = (unsigned short*)(ws + 20971520);         // 16,777,216
  unsigned short* Kb   = (unsigned short*)(ws + 37748736);         // 16,777,216
  unsigned short* Vb   = (unsigned short*)(ws + 54525952);         //  8,388,608
  unsigned short* Vtb  = (unsigned short*)(ws + 62914560);         //  8,388,608
  unsigned short* AOb  = (unsigned short*)(ws + 71303168);         //  8,388,608
  float*          proj = (float*)(ws + 79691776);                  // 16,777,216
  float*          lambp= (float*)(ws + 96468992);                  //  4

  dim3 tb(32,8);
  f32_to_bf16_k<<<4096, 256, 0, stream>>>(x, xb, 4194304);
  transpose_f32_bf16<<<dim3(64,32), tb, 0, stream>>>(Wq, WqT, 1024, 2048);
  transpose_f32_bf16<<<dim3(64,32), tb, 0, stream>>>(Wk, WkT, 1024, 2048);
  transpose_f32_bf16<<<dim3(32,32), tb, 0, stream>>>(Wv, WvT, 1024, 1024);
  transpose_f32_bf16<<<dim3(32,32), tb, 0, stream>>>(Wo, WoT, 1024, 1024);
  lamb_k<<<1, 64, 0, stream>>>(lq1, lk1, lq2, lk2, lambp);

  gemm_bt<unsigned short><<<dim3(32,16), 256, 0, stream>>>(xb, WqT, Qb, 4096, 2048, 1024);
  gemm_bt<unsigned short><<<dim3(32,16), 256, 0, stream>>>(xb, WkT, Kb, 4096, 2048, 1024);
  gemm_bt<unsigned short><<<dim3(32,8),  256, 0, stream>>>(xb, WvT, Vb, 4096, 1024, 1024);
  transpose_bf16<<<dim3(32,128), tb, 0, stream>>>(Vb, Vtb, 4096, 1024);

  diff_attn<<<dim3(32,16,2), 256, 0, stream>>>(Qb, Kb, Vtb, lambp, AOb);

  gemm_bt<float><<<dim3(32,8), 256, 0, stream>>>(AOb, WoT, proj, 4096, 1024, 1024);
  ln_k<<<4096, 256, 0, stream>>>(proj, gamma, beta, out);
}

// Round 4
// 312.228 us; speedup vs baseline: 2.3262x; 2.3262x over previous
//
#include <hip/hip_runtime.h>
#include <hip/hip_bf16.h>

typedef short bf16x8 __attribute__((ext_vector_type(8)));
typedef float f32x4 __attribute__((ext_vector_type(4)));
typedef unsigned short us4v __attribute__((ext_vector_type(4)));

#define DEV static __device__ __forceinline__

DEV float bf2f(unsigned short u){ unsigned int x = ((unsigned int)u)<<16; float f; __builtin_memcpy(&f,&x,4); return f; }
DEV unsigned short f2bf(float f){ unsigned int x; __builtin_memcpy(&x,&f,4); x = (x + 0x7fffu + ((x>>16)&1u)) >> 16; return (unsigned short)x; }
DEV unsigned int pack_bf16x2(float lo, float hi){
  __hip_bfloat162 h = __float22bfloat162_rn(float2{lo, hi});
  unsigned int u; __builtin_memcpy(&u, &h, 4); return u;
}

DEV void stor(unsigned short* p, float v){ *p = f2bf(v); }
DEV void stor(float* p, float v){ *p = v; }

#define GLOAD_LDS16(gptr, lptr) \
  __builtin_amdgcn_global_load_lds((__attribute__((address_space(1))) void*)(gptr), \
      (__attribute__((address_space(3))) void*)(lptr), 16, 0, 0)

// C = A[M,K] @ Bt[N,K]^T, bf16 inputs, OutT output. 128x128 tile, BK=32, 4 waves.
template<typename OutT>
__global__ __launch_bounds__(256) void gemm_bt(
    const unsigned short* __restrict__ A,
    const unsigned short* __restrict__ Bt,
    OutT* __restrict__ C, int M, int N, int K)
{
  __shared__ unsigned short As[128*32];
  __shared__ unsigned short Bs[128*32];
  const int tid = threadIdx.x;
  const int w = tid>>6, l = tid&63, g = l>>4, q = l&15;
  const int m0 = blockIdx.x*128, n0 = blockIdx.y*128;
  f32x4 acc[4][4];
  const f32x4 fz = {0.f,0.f,0.f,0.f};
  for (int i=0;i<4;i++) for(int j=0;j<4;j++) acc[i][j] = fz;
  for (int k0 = 0; k0 < K; k0 += 32) {
    __syncthreads();
    #pragma unroll
    for (int r = 0; r < 2; ++r) {
      int p = r*4096 + tid*16;
      int row = p>>6, colb = p&63;
      const char* ga = (const char*)(A  + (size_t)(m0+row)*K + k0) + colb;
      const char* gb = (const char*)(Bt + (size_t)(n0+row)*K + k0) + colb;
      GLOAD_LDS16(ga, (char*)As + r*4096 + w*1024);
      GLOAD_LDS16(gb, (char*)Bs + r*4096 + w*1024);
    }
    __syncthreads();
    bf16x8 af[4], bfr[4];
    #pragma unroll
    for (int i=0;i<4;i++){
      af[i]  = *(const bf16x8*)&As[((w>>1)*64 + i*16 + q)*32 + g*8];
      bfr[i] = *(const bf16x8*)&Bs[((w&1)*64 + i*16 + q)*32 + g*8];
    }
    #pragma unroll
    for (int i=0;i<4;i++)
      #pragma unroll
      for (int j=0;j<4;j++)
        acc[i][j] = __builtin_amdgcn_mfma_f32_16x16x32_bf16(af[i], bfr[j], acc[i][j], 0,0,0);
  }
  #pragma unroll
  for (int i=0;i<4;i++)
    #pragma unroll
    for (int j=0;j<4;j++)
      #pragma unroll
      for (int v=0;v<4;v++){
        int row = m0 + (w>>1)*64 + i*16 + g*4 + v;
        int col = n0 + (w&1)*64 + j*16 + q;
        stor(&C[(size_t)row*N + col], acc[i][j][v]);
      }
}

// Differential flash attention (round-2 structure + T14 async-stage split).
// Q,K: [4096][2048] bf16 (per head: Q1|Q2 / K1|K2). Vt: [1024][4096] bf16.
// aout: [4096][1024] bf16.
// LDS: Ks [64][128] XOR-swizzled (granule ^= row&7), Vs [64][64] swizzled,
// P12 per-wave [16][64] u32 (bf16 p1 | p2<<16) swizzled. Total 40960 B.
// Per tile: loads for tile t+1 are issued into registers BEFORE compute(t);
// only the ds_writes sit between the barriers.
__global__ __launch_bounds__(256,4) void diff_attn(
    const unsigned short* __restrict__ Q,
    const unsigned short* __restrict__ K,
    const unsigned short* __restrict__ Vt,
    const float* __restrict__ lambp,
    unsigned short* __restrict__ aout)
{
  __shared__ unsigned short Ks[64*128];   // 16 KiB
  __shared__ unsigned short Vs[64*64];    //  8 KiB
  __shared__ unsigned int  P12[4][16*64]; // 16 KiB
  const int tid = threadIdx.x, w = tid>>6, l = tid&63, g = l>>4, q = l&15;
  const int qb = blockIdx.x, h = blockIdx.y, b = blockIdx.z;
  const int qrow0 = b*2048 + qb*64 + w*16;

  // Q fragments, scaled by 1/8 (exact in bf16)
  bf16x8 q1f[2], q2f[2];
  {
    const unsigned short* qp = Q + (size_t)(qrow0 + q)*2048 + h*128;
    #pragma unroll
    for (int kf=0;kf<2;kf++){
      bf16x8 t1 = *(const bf16x8*)(qp + kf*32 + g*8);
      bf16x8 t2 = *(const bf16x8*)(qp + 64 + kf*32 + g*8);
      #pragma unroll
      for (int e=0;e<8;e++){
        t1[e] = (short)f2bf(bf2f((unsigned short)t1[e]) * 0.125f);
        t2[e] = (short)f2bf(bf2f((unsigned short)t2[e]) * 0.125f);
      }
      q1f[kf]=t1; q2f[kf]=t2;
    }
  }
  float s1[4], s2[4];
  f32x4 acc1[4], acc2[4];
  const f32x4 fz = {0.f,0.f,0.f,0.f};
  #pragma unroll
  for (int i=0;i<4;i++){ s1[i]=0.f; s2[i]=0.f; acc1[i]=fz; acc2[i]=fz; }

  const int rowl = tid & 63;
  const int swl = rowl & 7;
  const unsigned short* srcK0 = K + (size_t)(b*2048 + rowl)*2048 + h*128;
  const unsigned short* srcV0 = Vt + (size_t)(h*64 + rowl)*4096 + b*2048;

  // T14: staging registers for the next tile
  bf16x8 kreg[4], vreg[2];

  auto LOADT = [&](int kt){
    int ktc = kt & 2047;  // final wasted prefetch clamps to tile 0 (harmless)
    const unsigned short* srcK = srcK0 + (size_t)ktc*2048;
    #pragma unroll
    for (int c=0;c<4;c++) kreg[c] = *(const bf16x8*)(srcK + (w + c*4)*8);
    const unsigned short* srcV = srcV0 + ktc;
    #pragma unroll
    for (int c=0;c<2;c++) vreg[c] = *(const bf16x8*)(srcV + (w + c*4)*8);
  };
  auto WRITET = [&](){
    #pragma unroll
    for (int c=0;c<4;c++){
      int ch = w + c*4;
      *(bf16x8*)&Ks[rowl*128 + (ch^swl)*8] = kreg[c];
    }
    #pragma unroll
    for (int c=0;c<2;c++){
      int ch = w + c*4;
      *(bf16x8*)&Vs[rowl*64 + (ch^swl)*8] = vreg[c];
    }
  };

  LOADT(0);
  for (int kt=0; kt<2048; kt+=64) {
    __syncthreads();          // previous tile's compute done reading LDS
    WRITET();                 // commit tile kt to LDS
    __syncthreads();
    LOADT(kt+64);             // issue next tile's loads; land during compute
    // ---- compute on tile kt ----
    const int sw = q & 7;
    #pragma unroll
    for (int fn=0; fn<4; ++fn) {
      int krow = fn*16 + q;
      bf16x8 kb0 = *(const bf16x8*)&Ks[krow*128 + ((0*4+g)^sw)*8];
      bf16x8 kb1 = *(const bf16x8*)&Ks[krow*128 + ((1*4+g)^sw)*8];
      bf16x8 kc0 = *(const bf16x8*)&Ks[krow*128 + ((2*4+g)^sw)*8];
      bf16x8 kc1 = *(const bf16x8*)&Ks[krow*128 + ((3*4+g)^sw)*8];
      f32x4 z = fz, z2 = fz;
      z  = __builtin_amdgcn_mfma_f32_16x16x32_bf16(q1f[0], kb0, z, 0,0,0);
      z  = __builtin_amdgcn_mfma_f32_16x16x32_bf16(q1f[1], kb1, z, 0,0,0);
      z2 = __builtin_amdgcn_mfma_f32_16x16x32_bf16(q2f[0], kc0, z2, 0,0,0);
      z2 = __builtin_amdgcn_mfma_f32_16x16x32_bf16(q2f[1], kc1, z2, 0,0,0);
      #pragma unroll
      for (int i=0;i<4;i++){
        float p1 = __expf(z[i]);
        float p2 = __expf(z2[i]);
        unsigned int pk = pack_bf16x2(p1, p2);
        int row = g*4+i;
        P12[w][row*64 + (((fn*4 + (q>>2)) ^ (row&7))<<2) + (q&3)] = pk;
        s1[i] += bf2f((unsigned short)pk);
        s2[i] += bf2f((unsigned short)(pk>>16));
      }
    }
    // PV: A = P[q][key] (de-interleaved), B = V^T[d][key]
    #pragma unroll
    for (int kh=0; kh<2; ++kh) {
      int g0 = (kh*8 + g*2)     ^ sw;
      int g1 = (kh*8 + g*2 + 1) ^ sw;
      uint4 r0 = *(const uint4*)&P12[w][q*64 + g0*4];
      uint4 r1 = *(const uint4*)&P12[w][q*64 + g1*4];
      bf16x8 pa1, pa2;
      unsigned int* a1 = (unsigned int*)&pa1;
      unsigned int* a2 = (unsigned int*)&pa2;
      a1[0] = (r0.x & 0xffffu) | (r0.y << 16);
      a2[0] = (r0.x >> 16)     | (r0.y & 0xffff0000u);
      a1[1] = (r0.z & 0xffffu) | (r0.w << 16);
      a2[1] = (r0.z >> 16)     | (r0.w & 0xffff0000u);
      a1[2] = (r1.x & 0xffffu) | (r1.y << 16);
      a2[2] = (r1.x >> 16)     | (r1.y & 0xffff0000u);
      a1[3] = (r1.z & 0xffffu) | (r1.w << 16);
      a2[3] = (r1.z >> 16)     | (r1.w & 0xffff0000u);
      #pragma unroll
      for (int fd=0; fd<4; ++fd) {
        int vrow = fd*16 + q;
        bf16x8 vb = *(const bf16x8*)&Vs[vrow*64 + ((kh*4+g)^sw)*8];
        acc1[fd] = __builtin_amdgcn_mfma_f32_16x16x32_bf16(pa1, vb, acc1[fd], 0,0,0);
        acc2[fd] = __builtin_amdgcn_mfma_f32_16x16x32_bf16(pa2, vb, acc2[fd], 0,0,0);
      }
    }
  }
  // final row sums (keys spread over the 16 q-lanes of this g-group)
  #pragma unroll
  for (int i=0;i<4;i++){
    #pragma unroll
    for (int o=1;o<16;o<<=1){ s1[i] += __shfl_xor(s1[i],o); s2[i] += __shfl_xor(s2[i],o); }
  }
  float lamb = lambp[0];
  float inv1[4], inv2[4];
  #pragma unroll
  for (int i=0;i<4;i++){ inv1[i] = 1.0f/s1[i]; inv2[i] = lamb/s2[i]; }
  #pragma unroll
  for (int fd=0; fd<4; ++fd)
    #pragma unroll
    for (int i=0;i<4;i++){
      float val = acc1[fd][i]*inv1[i] - acc2[fd][i]*inv2[i];
      int row = qrow0 + g*4 + i;
      int col = h*64 + fd*16 + q;
      aout[(size_t)row*1024 + col] = f2bf(val);
    }
}

__global__ __launch_bounds__(256) void f32_to_bf16_k(const float* __restrict__ in, unsigned short* __restrict__ out, int n){
  int i = (blockIdx.x*256 + threadIdx.x)*4;
  if (i >= n) return;
  float4 vv = *(const float4*)(in + i);
  us4v o; o[0]=f2bf(vv.x); o[1]=f2bf(vv.y); o[2]=f2bf(vv.z); o[3]=f2bf(vv.w);
  *(us4v*)(out + i) = o;
}

// in: [R][C] f32 -> out: [C][R] bf16
__global__ void transpose_f32_bf16(const float* __restrict__ in, unsigned short* __restrict__ out, int R, int C){
  __shared__ unsigned short t[32][33];
  int c0 = blockIdx.x*32, r0 = blockIdx.y*32;
  int x = threadIdx.x, y = threadIdx.y;
  #pragma unroll
  for (int d=0; d<32; d+=8) t[y+d][x] = f2bf(in[(size_t)(r0+y+d)*C + c0 + x]);
  __syncthreads();
  #pragma unroll
  for (int d=0; d<32; d+=8) out[(size_t)(c0+y+d)*R + r0 + x] = t[x][y+d];
}

// in: [R][C] bf16 -> out: [C][R] bf16
__global__ void transpose_bf16(const unsigned short* __restrict__ in, unsigned short* __restrict__ out, int R, int C){
  __shared__ unsigned short t[32][33];
  int c0 = blockIdx.x*32, r0 = blockIdx.y*32;
  int x = threadIdx.x, y = threadIdx.y;
  #pragma unroll
  for (int d=0; d<32; d+=8) t[y+d][x] = in[(size_t)(r0+y+d)*C + c0 + x];
  __syncthreads();
  #pragma unroll
  for (int d=0; d<32; d+=8) out[(size_t)(c0+y+d)*R + r0 + x] = t[x][y+d];
}

__global__ void lamb_k(const float* lq1, const float* lk1, const float* lq2, const float* lk2, float* out){
  int i = threadIdx.x;
  float a = lq1[i]*lk1[i], c = lq2[i]*lk2[i];
  #pragma unroll
  for (int o=32;o>0;o>>=1){ a += __shfl_down(a,o); c += __shfl_down(c,o); }
  if (i==0) out[0] = expf(a) - expf(c) + 0.7778700995592560f; // LAMBDA_INIT for layer 12
}

__global__ __launch_bounds__(256) void ln_k(const float* __restrict__ in, const float* __restrict__ gam,
                                            const float* __restrict__ bet, float* __restrict__ out){
  int row = blockIdx.x, t = threadIdx.x;
  const float4* rp = (const float4*)(in + (size_t)row*1024);
  float4 v4 = rp[t];
  float s = v4.x+v4.y+v4.z+v4.w;
  float ss = v4.x*v4.x+v4.y*v4.y+v4.z*v4.z+v4.w*v4.w;
  #pragma unroll
  for (int o=1;o<64;o<<=1){ s += __shfl_xor(s,o); ss += __shfl_xor(ss,o); }
  __shared__ float red[8];
  int w = t>>6, l = t&63;
  if (l==0){ red[w]=s; red[4+w]=ss; }
  __syncthreads();
  s = red[0]+red[1]+red[2]+red[3];
  ss = red[4]+red[5]+red[6]+red[7];
  float mean = s*(1.0f/1024.0f);
  float var = ss*(1.0f/1024.0f) - mean*mean;
  float rstd = rsqrtf(var + 1e-5f);
  float4 gv = ((const float4*)gam)[t], bv = ((const float4*)bet)[t];
  float4 o;
  o.x = (v4.x-mean)*rstd*gv.x + bv.x;
  o.y = (v4.y-mean)*rstd*gv.y + bv.y;
  o.z = (v4.z-mean)*rstd*gv.z + bv.z;
  o.w = (v4.w-mean)*rstd*gv.w + bv.w;
  ((float4*)(out + (size_t)row*1024))[t] = o;
}

extern "C" void kernel_launch(void* const* d_in, const int* in_sizes, int n_in,
                              void* d_out, int out_size, void* d_ws, size_t ws_size,
                              hipStream_t stream) {
  const float* x     = (const float*)d_in[0];
  const float* Wq    = (const float*)d_in[1];
  const float* Wk    = (const float*)d_in[2];
  const float* Wv    = (const float*)d_in[3];
  const float* Wo    = (const float*)d_in[4];
  const float* lq1   = (const float*)d_in[5];
  const float* lk1   = (const float*)d_in[6];
  const float* lq2   = (const float*)d_in[7];
  const float* lk2   = (const float*)d_in[8];
  const float* gamma = (const float*)d_in[9];
  const float* beta  = (const float*)d_in[10];
  float* out = (float*)d_out;

  char* ws = (char*)d_ws;
  unsigned short* xb   = (unsigned short*)(ws);                    //  8,388,608 B
  unsigned short* WqT  = (unsigned short*)(ws + 8388608);          //  4,194,304
  unsigned short* WkT  = (unsigned short*)(ws + 12582912);         //  4,194,304
  unsigned short* WvT  = (unsigned short*)(ws + 16777216);         //  2,097,152
  unsigned short* WoT  = (unsigned short*)(ws + 18874368);         //  2,097,152
  unsigned short* Qb   = (unsigned short*)(ws + 20971520);         // 16,777,216
  unsigned short* Kb   = (unsigned short*)(ws + 37748736);         // 16,777,216
  unsigned short* Vb   = (unsigned short*)(ws + 54525952);         //  8,388,608
  unsigned short* Vtb  = (unsigned short*)(ws + 62914560);         //  8,388,608
  unsigned short* AOb  = (unsigned short*)(ws + 71303168);         //  8,388,608
  float*          proj = (float*)(ws + 79691776);                  // 16,777,216
  float*          lambp= (float*)(ws + 96468992);                  //  4

  dim3 tb(32,8);
  f32_to_bf16_k<<<4096, 256, 0, stream>>>(x, xb, 4194304);
  transpose_f32_bf16<<<dim3(64,32), tb, 0, stream>>>(Wq, WqT, 1024, 2048);
  transpose_f32_bf16<<<dim3(64,32), tb, 0, stream>>>(Wk, WkT, 1024, 2048);
  transpose_f32_bf16<<<dim3(32,32), tb, 0, stream>>>(Wv, WvT, 1024, 1024);
  transpose_f32_bf16<<<dim3(32,32), tb, 0, stream>>>(Wo, WoT, 1024, 1024);
  lamb_k<<<1, 64, 0, stream>>>(lq1, lk1, lq2, lk2, lambp);

  gemm_bt<unsigned short><<<dim3(32,16), 256, 0, stream>>>(xb, WqT, Qb, 4096, 2048, 1024);
  gemm_bt<unsigned short><<<dim3(32,16), 256, 0, stream>>>(xb, WkT, Kb, 4096, 2048, 1024);
  gemm_bt<unsigned short><<<dim3(32,8),  256, 0, stream>>>(xb, WvT, Vb, 4096, 1024, 1024);
  transpose_bf16<<<dim3(32,128), tb, 0, stream>>>(Vb, Vtb, 4096, 1024);

  diff_attn<<<dim3(32,16,2), 256, 0, stream>>>(Qb, Kb, Vtb, lambp, AOb);

  gemm_bt<float><<<dim3(32,8), 256, 0, stream>>>(AOb, WoT, proj, 4096, 1024, 1024);
  ln_k<<<4096, 256, 0, stream>>>(proj, gamma, beta, out);
}

// Round 5
// 278.011 us; speedup vs baseline: 2.6125x; 1.1231x over previous
//
#include <hip/hip_runtime.h>
#include <hip/hip_bf16.h>

typedef short bf16x8 __attribute__((ext_vector_type(8)));
typedef float f32x4 __attribute__((ext_vector_type(4)));
typedef unsigned short us4v __attribute__((ext_vector_type(4)));
typedef unsigned int uint2v __attribute__((ext_vector_type(2)));

#define DEV static __device__ __forceinline__

DEV float bf2f(unsigned short u){ unsigned int x = ((unsigned int)u)<<16; float f; __builtin_memcpy(&f,&x,4); return f; }
DEV unsigned short f2bf(float f){ unsigned int x; __builtin_memcpy(&x,&f,4); x = (x + 0x7fffu + ((x>>16)&1u)) >> 16; return (unsigned short)x; }
DEV unsigned int pack_bf16x2(float lo, float hi){
  __hip_bfloat162 h = __float22bfloat162_rn(float2{lo, hi});
  unsigned int u; __builtin_memcpy(&u, &h, 4); return u;
}

DEV void stor(unsigned short* p, float v){ *p = f2bf(v); }
DEV void stor(float* p, float v){ *p = v; }

#if __has_builtin(__builtin_amdgcn_permlane32_swap)
DEV uint2v pl32(unsigned int a, unsigned int b){ return __builtin_amdgcn_permlane32_swap(a, b, false, false); }
#else
DEV uint2v pl32(unsigned int a, unsigned int b){
  unsigned int sa = (unsigned int)__shfl_xor((int)a, 32);
  unsigned int sb = (unsigned int)__shfl_xor((int)b, 32);
  bool hi = (threadIdx.x & 32) != 0;
  uint2v r; r[0] = hi ? sb : a; r[1] = hi ? b : sa; return r;
}
#endif
#if __has_builtin(__builtin_amdgcn_permlane16_swap)
DEV uint2v pl16(unsigned int a, unsigned int b){ return __builtin_amdgcn_permlane16_swap(a, b, false, false); }
#else
DEV uint2v pl16(unsigned int a, unsigned int b){
  unsigned int sa = (unsigned int)__shfl_xor((int)a, 16);
  unsigned int sb = (unsigned int)__shfl_xor((int)b, 16);
  bool hi = (threadIdx.x & 16) != 0;
  uint2v r; r[0] = hi ? sb : a; r[1] = hi ? b : sa; return r;
}
#endif

#define GLOAD_LDS16(gptr, lptr) \
  __builtin_amdgcn_global_load_lds((__attribute__((address_space(1))) void*)(gptr), \
      (__attribute__((address_space(3))) void*)(lptr), 16, 0, 0)

// C = A[M,K] @ Bt[N,K]^T, bf16 inputs, OutT output. 128x128 tile, BK=32, 4 waves.
template<typename OutT>
__global__ __launch_bounds__(256) void gemm_bt(
    const unsigned short* __restrict__ A,
    const unsigned short* __restrict__ Bt,
    OutT* __restrict__ C, int M, int N, int K)
{
  __shared__ unsigned short As[128*32];
  __shared__ unsigned short Bs[128*32];
  const int tid = threadIdx.x;
  const int w = tid>>6, l = tid&63, g = l>>4, q = l&15;
  const int m0 = blockIdx.x*128, n0 = blockIdx.y*128;
  f32x4 acc[4][4];
  const f32x4 fz = {0.f,0.f,0.f,0.f};
  for (int i=0;i<4;i++) for(int j=0;j<4;j++) acc[i][j] = fz;
  for (int k0 = 0; k0 < K; k0 += 32) {
    __syncthreads();
    #pragma unroll
    for (int r = 0; r < 2; ++r) {
      int p = r*4096 + tid*16;
      int row = p>>6, colb = p&63;
      const char* ga = (const char*)(A  + (size_t)(m0+row)*K + k0) + colb;
      const char* gb = (const char*)(Bt + (size_t)(n0+row)*K + k0) + colb;
      GLOAD_LDS16(ga, (char*)As + r*4096 + w*1024);
      GLOAD_LDS16(gb, (char*)Bs + r*4096 + w*1024);
    }
    __syncthreads();
    bf16x8 af[4], bfr[4];
    #pragma unroll
    for (int i=0;i<4;i++){
      af[i]  = *(const bf16x8*)&As[((w>>1)*64 + i*16 + q)*32 + g*8];
      bfr[i] = *(const bf16x8*)&Bs[((w&1)*64 + i*16 + q)*32 + g*8];
    }
    #pragma unroll
    for (int i=0;i<4;i++)
      #pragma unroll
      for (int j=0;j<4;j++)
        acc[i][j] = __builtin_amdgcn_mfma_f32_16x16x32_bf16(af[i], bfr[j], acc[i][j], 0,0,0);
  }
  #pragma unroll
  for (int i=0;i<4;i++)
    #pragma unroll
    for (int j=0;j<4;j++)
      #pragma unroll
      for (int v=0;v<4;v++){
        int row = m0 + (w>>1)*64 + i*16 + g*4 + v;
        int col = n0 + (w&1)*64 + j*16 + q;
        stor(&C[(size_t)row*N + col], acc[i][j][v]);
      }
}

// Differential flash attention v5: swapped QK^T + in-register P via
// cvt_pk + permlane{32,16}_swap (T12). No P LDS round-trip.
// Q,K: [4096][2048] bf16 (per head: Q1|Q2 / K1|K2). Vt: [1024][4096] bf16.
// aout: [4096][1024] bf16.
// LDS: Ks [64][128] XOR-swizzled (granule ^= row&7), Vs [64][64] swizzled.
// Q is pre-scaled by 0.125*log2(e) so p = exp2(z) directly.
__global__ __launch_bounds__(256,4) void diff_attn(
    const unsigned short* __restrict__ Q,
    const unsigned short* __restrict__ K,
    const unsigned short* __restrict__ Vt,
    const float* __restrict__ lambp,
    unsigned short* __restrict__ aout)
{
  __shared__ unsigned short Ks[64*128];   // 16 KiB
  __shared__ unsigned short Vs[64*64];    //  8 KiB
  const int tid = threadIdx.x, w = tid>>6, l = tid&63, g = l>>4, q = l&15;
  const int qb = blockIdx.x, h = blockIdx.y, b = blockIdx.z;
  const int qrow0 = b*2048 + qb*64 + w*16;
  const f32x4 fz = {0.f,0.f,0.f,0.f};

  // Q fragments, scaled by (1/8)*log2(e) so exp2 gives softmax numerator
  const float QSCALE = 0.125f * 1.4426950408889634f;
  bf16x8 q1f[2], q2f[2];
  {
    const unsigned short* qp = Q + (size_t)(qrow0 + q)*2048 + h*128;
    #pragma unroll
    for (int kf=0;kf<2;kf++){
      bf16x8 t1 = *(const bf16x8*)(qp + kf*32 + g*8);
      bf16x8 t2 = *(const bf16x8*)(qp + 64 + kf*32 + g*8);
      #pragma unroll
      for (int e=0;e<8;e++){
        t1[e] = (short)f2bf(bf2f((unsigned short)t1[e]) * QSCALE);
        t2[e] = (short)f2bf(bf2f((unsigned short)t2[e]) * QSCALE);
      }
      q1f[kf]=t1; q2f[kf]=t2;
    }
  }
  float s1p = 0.f, s2p = 0.f;
  f32x4 acc1[4], acc2[4];
  #pragma unroll
  for (int i=0;i<4;i++){ acc1[i]=fz; acc2[i]=fz; }

  const int rowl = tid & 63;
  const int swl = rowl & 7;
  const unsigned short* srcK0 = K + (size_t)(b*2048 + rowl)*2048 + h*128;
  const unsigned short* srcV0 = Vt + (size_t)(h*64 + rowl)*4096 + b*2048;

  bf16x8 kreg[4], vreg[2];
  auto LOADT = [&](int kt){
    int ktc = kt & 2047;  // final wasted prefetch clamps (harmless)
    const unsigned short* srcK = srcK0 + (size_t)ktc*2048;
    #pragma unroll
    for (int c=0;c<4;c++) kreg[c] = *(const bf16x8*)(srcK + (w + c*4)*8);
    const unsigned short* srcV = srcV0 + ktc;
    #pragma unroll
    for (int c=0;c<2;c++) vreg[c] = *(const bf16x8*)(srcV + (w + c*4)*8);
  };
  auto WRITET = [&](){
    #pragma unroll
    for (int c=0;c<4;c++){
      int ch = w + c*4;
      *(bf16x8*)&Ks[rowl*128 + (ch^swl)*8] = kreg[c];
    }
    #pragma unroll
    for (int c=0;c<2;c++){
      int ch = w + c*4;
      *(bf16x8*)&Vs[rowl*64 + (ch^swl)*8] = vreg[c];
    }
  };

  LOADT(0);
  for (int kt=0; kt<2048; kt+=64) {
    __syncthreads();          // previous tile's compute done reading LDS
    WRITET();                 // commit tile kt to LDS
    __syncthreads();
    LOADT(kt+64);             // next tile's loads land during compute
    const int sw = q & 7;

    // ---- swapped QK^T: z[fn] = C[key=fn*16+g*4+i][qrow=q] ----
    unsigned int c1[4][2], c2[4][2];
    #pragma unroll
    for (int fn=0; fn<4; ++fn) {
      const unsigned short* kr = &Ks[(fn*16 + q)*128];
      bf16x8 kb0 = *(const bf16x8*)&kr[((0+g)^sw)*8];
      bf16x8 kb1 = *(const bf16x8*)&kr[((4+g)^sw)*8];
      bf16x8 kc0 = *(const bf16x8*)&kr[((8+g)^sw)*8];
      bf16x8 kc1 = *(const bf16x8*)&kr[((12+g)^sw)*8];
      f32x4 a = fz, c = fz;
      a = __builtin_amdgcn_mfma_f32_16x16x32_bf16(kb0, q1f[0], a, 0,0,0);
      a = __builtin_amdgcn_mfma_f32_16x16x32_bf16(kb1, q1f[1], a, 0,0,0);
      c = __builtin_amdgcn_mfma_f32_16x16x32_bf16(kc0, q2f[0], c, 0,0,0);
      c = __builtin_amdgcn_mfma_f32_16x16x32_bf16(kc1, q2f[1], c, 0,0,0);
      float e0 = exp2f(a[0]), e1 = exp2f(a[1]), e2 = exp2f(a[2]), e3 = exp2f(a[3]);
      s1p += (e0+e1)+(e2+e3);
      c1[fn][0] = pack_bf16x2(e0,e1); c1[fn][1] = pack_bf16x2(e2,e3);
      float f0 = exp2f(c[0]), f1 = exp2f(c[1]), f2 = exp2f(c[2]), f3 = exp2f(c[3]);
      s2p += (f0+f1)+(f2+f3);
      c2[fn][0] = pack_bf16x2(f0,f1); c2[fn][1] = pack_bf16x2(f2,f3);
    }

    // ---- in-register P -> A-frag via permlane swaps ----
    // target word m of pa[kh] at lane(b4,b5) = c[2kh + b5][m&1] from lane(b4'=m>>1, b5'=b4)
    bf16x8 pa1[2], pa2[2];
    #pragma unroll
    for (int kh=0; kh<2; ++kh){
      unsigned int* u1 = (unsigned int*)&pa1[kh];
      unsigned int* u2 = (unsigned int*)&pa2[kh];
      #pragma unroll
      for (int j=0;j<2;j++){
        uint2v d = pl32(c1[2*kh][j], c1[2*kh+1][j]);
        uint2v e = pl16(d[0], d[1]);
        u1[j] = e[0]; u1[2+j] = e[1];
        uint2v d2 = pl32(c2[2*kh][j], c2[2*kh+1][j]);
        uint2v e2 = pl16(d2[0], d2[1]);
        u2[j] = e2[0]; u2[2+j] = e2[1];
      }
    }

    // ---- PV ----
    #pragma unroll
    for (int kh=0; kh<2; ++kh){
      #pragma unroll
      for (int fd=0; fd<4; ++fd){
        bf16x8 vb = *(const bf16x8*)&Vs[(fd*16+q)*64 + ((kh*4+g)^sw)*8];
        acc1[fd] = __builtin_amdgcn_mfma_f32_16x16x32_bf16(pa1[kh], vb, acc1[fd], 0,0,0);
        acc2[fd] = __builtin_amdgcn_mfma_f32_16x16x32_bf16(pa2[kh], vb, acc2[fd], 0,0,0);
      }
    }
  }

  // denominators: per-lane partial covers qrow q, keys {fn*16+g*4+i}; reduce over g
  s1p += __shfl_xor(s1p, 16); s1p += __shfl_xor(s1p, 32);
  s2p += __shfl_xor(s2p, 16); s2p += __shfl_xor(s2p, 32);
  float lamb = lambp[0];
  float r1 = 1.0f/s1p, r2 = lamb/s2p;
  float inv1[4], inv2[4];
  #pragma unroll
  for (int i=0;i<4;i++){
    inv1[i] = __shfl(r1, g*4+i);
    inv2[i] = __shfl(r2, g*4+i);
  }
  #pragma unroll
  for (int fd=0; fd<4; ++fd)
    #pragma unroll
    for (int i=0;i<4;i++){
      float val = acc1[fd][i]*inv1[i] - acc2[fd][i]*inv2[i];
      int row = qrow0 + g*4 + i;
      int col = h*64 + fd*16 + q;
      aout[(size_t)row*1024 + col] = f2bf(val);
    }
}

__global__ __launch_bounds__(256) void f32_to_bf16_k(const float* __restrict__ in, unsigned short* __restrict__ out, int n){
  int i = (blockIdx.x*256 + threadIdx.x)*4;
  if (i >= n) return;
  float4 vv = *(const float4*)(in + i);
  us4v o; o[0]=f2bf(vv.x); o[1]=f2bf(vv.y); o[2]=f2bf(vv.z); o[3]=f2bf(vv.w);
  *(us4v*)(out + i) = o;
}

// in: [R][C] f32 -> out: [C][R] bf16
__global__ void transpose_f32_bf16(const float* __restrict__ in, unsigned short* __restrict__ out, int R, int C){
  __shared__ unsigned short t[32][33];
  int c0 = blockIdx.x*32, r0 = blockIdx.y*32;
  int x = threadIdx.x, y = threadIdx.y;
  #pragma unroll
  for (int d=0; d<32; d+=8) t[y+d][x] = f2bf(in[(size_t)(r0+y+d)*C + c0 + x]);
  __syncthreads();
  #pragma unroll
  for (int d=0; d<32; d+=8) out[(size_t)(c0+y+d)*R + r0 + x] = t[x][y+d];
}

// in: [R][C] bf16 -> out: [C][R] bf16
__global__ void transpose_bf16(const unsigned short* __restrict__ in, unsigned short* __restrict__ out, int R, int C){
  __shared__ unsigned short t[32][33];
  int c0 = blockIdx.x*32, r0 = blockIdx.y*32;
  int x = threadIdx.x, y = threadIdx.y;
  #pragma unroll
  for (int d=0; d<32; d+=8) t[y+d][x] = in[(size_t)(r0+y+d)*C + c0 + x];
  __syncthreads();
  #pragma unroll
  for (int d=0; d<32; d+=8) out[(size_t)(c0+y+d)*R + r0 + x] = t[x][y+d];
}

__global__ void lamb_k(const float* lq1, const float* lk1, const float* lq2, const float* lk2, float* out){
  int i = threadIdx.x;
  float a = lq1[i]*lk1[i], c = lq2[i]*lk2[i];
  #pragma unroll
  for (int o=32;o>0;o>>=1){ a += __shfl_down(a,o); c += __shfl_down(c,o); }
  if (i==0) out[0] = expf(a) - expf(c) + 0.7778700995592560f; // LAMBDA_INIT for layer 12
}

__global__ __launch_bounds__(256) void ln_k(const float* __restrict__ in, const float* __restrict__ gam,
                                            const float* __restrict__ bet, float* __restrict__ out){
  int row = blockIdx.x, t = threadIdx.x;
  const float4* rp = (const float4*)(in + (size_t)row*1024);
  float4 v4 = rp[t];
  float s = v4.x+v4.y+v4.z+v4.w;
  float ss = v4.x*v4.x+v4.y*v4.y+v4.z*v4.z+v4.w*v4.w;
  #pragma unroll
  for (int o=1;o<64;o<<=1){ s += __shfl_xor(s,o); ss += __shfl_xor(ss,o); }
  __shared__ float red[8];
  int w = t>>6, l = t&63;
  if (l==0){ red[w]=s; red[4+w]=ss; }
  __syncthreads();
  s = red[0]+red[1]+red[2]+red[3];
  ss = red[4]+red[5]+red[6]+red[7];
  float mean = s*(1.0f/1024.0f);
  float var = ss*(1.0f/1024.0f) - mean*mean;
  float rstd = rsqrtf(var + 1e-5f);
  float4 gv = ((const float4*)gam)[t], bv = ((const float4*)bet)[t];
  float4 o;
  o.x = (v4.x-mean)*rstd*gv.x + bv.x;
  o.y = (v4.y-mean)*rstd*gv.y + bv.y;
  o.z = (v4.z-mean)*rstd*gv.z + bv.z;
  o.w = (v4.w-mean)*rstd*gv.w + bv.w;
  ((float4*)(out + (size_t)row*1024))[t] = o;
}

extern "C" void kernel_launch(void* const* d_in, const int* in_sizes, int n_in,
                              void* d_out, int out_size, void* d_ws, size_t ws_size,
                              hipStream_t stream) {
  const float* x     = (const float*)d_in[0];
  const float* Wq    = (const float*)d_in[1];
  const float* Wk    = (const float*)d_in[2];
  const float* Wv    = (const float*)d_in[3];
  const float* Wo    = (const float*)d_in[4];
  const float* lq1   = (const float*)d_in[5];
  const float* lk1   = (const float*)d_in[6];
  const float* lq2   = (const float*)d_in[7];
  const float* lk2   = (const float*)d_in[8];
  const float* gamma = (const float*)d_in[9];
  const float* beta  = (const float*)d_in[10];
  float* out = (float*)d_out;

  char* ws = (char*)d_ws;
  unsigned short* xb   = (unsigned short*)(ws);                    //  8,388,608 B
  unsigned short* WqT  = (unsigned short*)(ws + 8388608);          //  4,194,304
  unsigned short* WkT  = (unsigned short*)(ws + 12582912);         //  4,194,304
  unsigned short* WvT  = (unsigned short*)(ws + 16777216);         //  2,097,152
  unsigned short* WoT  = (unsigned short*)(ws + 18874368);         //  2,097,152
  unsigned short* Qb   = (unsigned short*)(ws + 20971520);         // 16,777,216
  unsigned short* Kb   = (unsigned short*)(ws + 37748736);         // 16,777,216
  unsigned short* Vb   = (unsigned short*)(ws + 54525952);         //  8,388,608
  unsigned short* Vtb  = (unsigned short*)(ws + 62914560);         //  8,388,608
  unsigned short* AOb  = (unsigned short*)(ws + 71303168);         //  8,388,608
  float*          proj = (float*)(ws + 79691776);                  // 16,777,216
  float*          lambp= (float*)(ws + 96468992);                  //  4

  dim3 tb(32,8);
  f32_to_bf16_k<<<4096, 256, 0, stream>>>(x, xb, 4194304);
  transpose_f32_bf16<<<dim3(64,32), tb, 0, stream>>>(Wq, WqT, 1024, 2048);
  transpose_f32_bf16<<<dim3(64,32), tb, 0, stream>>>(Wk, WkT, 1024, 2048);
  transpose_f32_bf16<<<dim3(32,32), tb, 0, stream>>>(Wv, WvT, 1024, 1024);
  transpose_f32_bf16<<<dim3(32,32), tb, 0, stream>>>(Wo, WoT, 1024, 1024);
  lamb_k<<<1, 64, 0, stream>>>(lq1, lk1, lq2, lk2, lambp);

  gemm_bt<unsigned short><<<dim3(32,16), 256, 0, stream>>>(xb, WqT, Qb, 4096, 2048, 1024);
  gemm_bt<unsigned short><<<dim3(32,16), 256, 0, stream>>>(xb, WkT, Kb, 4096, 2048, 1024);
  gemm_bt<unsigned short><<<dim3(32,8),  256, 0, stream>>>(xb, WvT, Vb, 4096, 1024, 1024);
  transpose_bf16<<<dim3(32,128), tb, 0, stream>>>(Vb, Vtb, 4096, 1024);

  diff_attn<<<dim3(32,16,2), 256, 0, stream>>>(Qb, Kb, Vtb, lambp, AOb);

  gemm_bt<float><<<dim3(32,8), 256, 0, stream>>>(AOb, WoT, proj, 4096, 1024, 1024);
  ln_k<<<4096, 256, 0, stream>>>(proj, gamma, beta, out);
}

// Round 6
// 246.511 us; speedup vs baseline: 2.9463x; 1.1278x over previous
//
#include <hip/hip_runtime.h>
#include <hip/hip_bf16.h>

typedef short bf16x8 __attribute__((ext_vector_type(8)));
typedef float f32x4 __attribute__((ext_vector_type(4)));
typedef unsigned short us4v __attribute__((ext_vector_type(4)));
typedef unsigned int uint2v __attribute__((ext_vector_type(2)));

#define DEV static __device__ __forceinline__

DEV float bf2f(unsigned short u){ unsigned int x = ((unsigned int)u)<<16; float f; __builtin_memcpy(&f,&x,4); return f; }
DEV unsigned short f2bf(float f){ unsigned int x; __builtin_memcpy(&x,&f,4); x = (x + 0x7fffu + ((x>>16)&1u)) >> 16; return (unsigned short)x; }
DEV unsigned int pack_bf16x2(float lo, float hi){
  __hip_bfloat162 h = __float22bfloat162_rn(float2{lo, hi});
  unsigned int u; __builtin_memcpy(&u, &h, 4); return u;
}

DEV void stor(unsigned short* p, float v){ *p = f2bf(v); }
DEV void stor(float* p, float v){ *p = v; }

#if __has_builtin(__builtin_amdgcn_permlane32_swap)
DEV uint2v pl32(unsigned int a, unsigned int b){ return __builtin_amdgcn_permlane32_swap(a, b, false, false); }
#else
DEV uint2v pl32(unsigned int a, unsigned int b){
  unsigned int sa = (unsigned int)__shfl_xor((int)a, 32);
  unsigned int sb = (unsigned int)__shfl_xor((int)b, 32);
  bool hi = (threadIdx.x & 32) != 0;
  uint2v r; r[0] = hi ? sb : a; r[1] = hi ? b : sa; return r;
}
#endif
#if __has_builtin(__builtin_amdgcn_permlane16_swap)
DEV uint2v pl16(unsigned int a, unsigned int b){ return __builtin_amdgcn_permlane16_swap(a, b, false, false); }
#else
DEV uint2v pl16(unsigned int a, unsigned int b){
  unsigned int sa = (unsigned int)__shfl_xor((int)a, 16);
  unsigned int sb = (unsigned int)__shfl_xor((int)b, 16);
  bool hi = (threadIdx.x & 16) != 0;
  uint2v r; r[0] = hi ? sb : a; r[1] = hi ? b : sa; return r;
}
#endif

#define GLOAD_LDS16(gptr, lptr) \
  __builtin_amdgcn_global_load_lds((__attribute__((address_space(1))) void*)(gptr), \
      (__attribute__((address_space(3))) void*)(lptr), 16, 0, 0)

// C = A[M,K] @ Bt[N,K]^T, bf16 inputs, OutT output. 128x128 tile, BK=32, 4 waves.
template<typename OutT>
__global__ __launch_bounds__(256) void gemm_bt(
    const unsigned short* __restrict__ A,
    const unsigned short* __restrict__ Bt,
    OutT* __restrict__ C, int M, int N, int K)
{
  __shared__ unsigned short As[128*32];
  __shared__ unsigned short Bs[128*32];
  const int tid = threadIdx.x;
  const int w = tid>>6, l = tid&63, g = l>>4, q = l&15;
  const int m0 = blockIdx.x*128, n0 = blockIdx.y*128;
  f32x4 acc[4][4];
  const f32x4 fz = {0.f,0.f,0.f,0.f};
  for (int i=0;i<4;i++) for(int j=0;j<4;j++) acc[i][j] = fz;
  for (int k0 = 0; k0 < K; k0 += 32) {
    __syncthreads();
    #pragma unroll
    for (int r = 0; r < 2; ++r) {
      int p = r*4096 + tid*16;
      int row = p>>6, colb = p&63;
      const char* ga = (const char*)(A  + (size_t)(m0+row)*K + k0) + colb;
      const char* gb = (const char*)(Bt + (size_t)(n0+row)*K + k0) + colb;
      GLOAD_LDS16(ga, (char*)As + r*4096 + w*1024);
      GLOAD_LDS16(gb, (char*)Bs + r*4096 + w*1024);
    }
    __syncthreads();
    bf16x8 af[4], bfr[4];
    #pragma unroll
    for (int i=0;i<4;i++){
      af[i]  = *(const bf16x8*)&As[((w>>1)*64 + i*16 + q)*32 + g*8];
      bfr[i] = *(const bf16x8*)&Bs[((w&1)*64 + i*16 + q)*32 + g*8];
    }
    #pragma unroll
    for (int i=0;i<4;i++)
      #pragma unroll
      for (int j=0;j<4;j++)
        acc[i][j] = __builtin_amdgcn_mfma_f32_16x16x32_bf16(af[i], bfr[j], acc[i][j], 0,0,0);
  }
  #pragma unroll
  for (int i=0;i<4;i++)
    #pragma unroll
    for (int j=0;j<4;j++)
      #pragma unroll
      for (int v=0;v<4;v++){
        int row = m0 + (w>>1)*64 + i*16 + g*4 + v;
        int col = n0 + (w&1)*64 + j*16 + q;
        stor(&C[(size_t)row*N + col], acc[i][j][v]);
      }
}

// Differential flash attention v6: 32 q-rows per wave (128 q/block),
// swapped QK^T + in-register P via cvt_pk + permlane{32,16}_swap.
// Qp/Kp rows have ld=5120 (merged QKV layout); per head cols h*128..h*128+127.
// Vt: [1024][4096] bf16. aout: [4096][1024] bf16.
// LDS: Ks [64][128] XOR-swizzled (granule ^= row&7), Vs [64][64] swizzled.
// Q pre-scaled by 0.125*log2(e) so p = exp2(z).
__global__ __launch_bounds__(256,2) void diff_attn(
    const unsigned short* __restrict__ Qp,
    const unsigned short* __restrict__ Kp,
    const unsigned short* __restrict__ Vt,
    const float* __restrict__ lambp,
    unsigned short* __restrict__ aout)
{
  const int LDQ = 5120;
  __shared__ unsigned short Ks[64*128];   // 16 KiB
  __shared__ unsigned short Vs[64*64];    //  8 KiB
  const int tid = threadIdx.x, w = tid>>6, l = tid&63, g = l>>4, q = l&15;
  const int qb = blockIdx.x, h = blockIdx.y, b = blockIdx.z;
  const int qrow0 = b*2048 + qb*128 + w*32;
  const f32x4 fz = {0.f,0.f,0.f,0.f};

  // Q fragments for 2 q-subtiles, scaled by (1/8)*log2(e)
  const float QSCALE = 0.125f * 1.4426950408889634f;
  bf16x8 q1f[2][2], q2f[2][2];
  #pragma unroll
  for (int qh=0; qh<2; ++qh){
    const unsigned short* qp = Qp + (size_t)(qrow0 + qh*16 + q)*LDQ + h*128;
    #pragma unroll
    for (int kf=0;kf<2;kf++){
      bf16x8 t1 = *(const bf16x8*)(qp + kf*32 + g*8);
      bf16x8 t2 = *(const bf16x8*)(qp + 64 + kf*32 + g*8);
      #pragma unroll
      for (int e=0;e<8;e++){
        t1[e] = (short)f2bf(bf2f((unsigned short)t1[e]) * QSCALE);
        t2[e] = (short)f2bf(bf2f((unsigned short)t2[e]) * QSCALE);
      }
      q1f[qh][kf]=t1; q2f[qh][kf]=t2;
    }
  }
  float s1p[2] = {0.f, 0.f}, s2p[2] = {0.f, 0.f};
  f32x4 acc1[2][4], acc2[2][4];
  #pragma unroll
  for (int qh=0;qh<2;qh++)
    #pragma unroll
    for (int i=0;i<4;i++){ acc1[qh][i]=fz; acc2[qh][i]=fz; }

  const int rowl = l;
  const int swl = rowl & 7;
  const unsigned short* pK = Kp + (size_t)(b*2048 + rowl)*LDQ + h*128;
  const unsigned short* pV = Vt + (size_t)(h*64 + rowl)*4096 + b*2048;

  bf16x8 kreg[4], vreg[2];
  auto LOADT = [&](){
    #pragma unroll
    for (int c=0;c<4;c++) kreg[c] = *(const bf16x8*)(pK + (w + c*4)*8);
    #pragma unroll
    for (int c=0;c<2;c++) vreg[c] = *(const bf16x8*)(pV + (w + c*4)*8);
    pK += (size_t)64*LDQ;
    pV += 64;
  };
  auto WRITET = [&](){
    #pragma unroll
    for (int c=0;c<4;c++){
      int ch = w + c*4;
      *(bf16x8*)&Ks[rowl*128 + (ch^swl)*8] = kreg[c];
    }
    #pragma unroll
    for (int c=0;c<2;c++){
      int ch = w + c*4;
      *(bf16x8*)&Vs[rowl*64 + (ch^swl)*8] = vreg[c];
    }
  };

  LOADT();
  for (int t=0; t<32; ++t) {
    __syncthreads();          // previous tile's compute done reading LDS
    WRITET();                 // commit tile t to LDS
    __syncthreads();
    if (t < 31) LOADT();      // next tile's loads land during compute
    const int sw = q & 7;

    // ---- swapped QK^T: per qh, z[fn] = C[key=fn*16+g*4+i][qrow] ----
    unsigned int c1[2][4][2], c2[2][4][2];
    #pragma unroll
    for (int fn=0; fn<4; ++fn) {
      const unsigned short* kr = &Ks[(fn*16 + q)*128];
      bf16x8 kb0 = *(const bf16x8*)&kr[((0+g)^sw)*8];
      bf16x8 kb1 = *(const bf16x8*)&kr[((4+g)^sw)*8];
      bf16x8 kc0 = *(const bf16x8*)&kr[((8+g)^sw)*8];
      bf16x8 kc1 = *(const bf16x8*)&kr[((12+g)^sw)*8];
      f32x4 za[2], zc[2];
      __builtin_amdgcn_s_setprio(1);
      #pragma unroll
      for (int qh=0; qh<2; ++qh){
        f32x4 a = fz, c = fz;
        a = __builtin_amdgcn_mfma_f32_16x16x32_bf16(kb0, q1f[qh][0], a, 0,0,0);
        a = __builtin_amdgcn_mfma_f32_16x16x32_bf16(kb1, q1f[qh][1], a, 0,0,0);
        c = __builtin_amdgcn_mfma_f32_16x16x32_bf16(kc0, q2f[qh][0], c, 0,0,0);
        c = __builtin_amdgcn_mfma_f32_16x16x32_bf16(kc1, q2f[qh][1], c, 0,0,0);
        za[qh]=a; zc[qh]=c;
      }
      __builtin_amdgcn_s_setprio(0);
      #pragma unroll
      for (int qh=0; qh<2; ++qh){
        float e0 = exp2f(za[qh][0]), e1 = exp2f(za[qh][1]);
        float e2 = exp2f(za[qh][2]), e3 = exp2f(za[qh][3]);
        s1p[qh] += (e0+e1)+(e2+e3);
        c1[qh][fn][0] = pack_bf16x2(e0,e1); c1[qh][fn][1] = pack_bf16x2(e2,e3);
        float f0 = exp2f(zc[qh][0]), f1 = exp2f(zc[qh][1]);
        float f2 = exp2f(zc[qh][2]), f3 = exp2f(zc[qh][3]);
        s2p[qh] += (f0+f1)+(f2+f3);
        c2[qh][fn][0] = pack_bf16x2(f0,f1); c2[qh][fn][1] = pack_bf16x2(f2,f3);
      }
    }

    // ---- in-register P -> A-frag via permlane swaps (per qh) ----
    bf16x8 pa1[2][2], pa2[2][2];
    #pragma unroll
    for (int qh=0; qh<2; ++qh)
      #pragma unroll
      for (int kh=0; kh<2; ++kh){
        unsigned int* u1 = (unsigned int*)&pa1[qh][kh];
        unsigned int* u2 = (unsigned int*)&pa2[qh][kh];
        #pragma unroll
        for (int j=0;j<2;j++){
          uint2v d = pl32(c1[qh][2*kh][j], c1[qh][2*kh+1][j]);
          uint2v e = pl16(d[0], d[1]);
          u1[j] = e[0]; u1[2+j] = e[1];
          uint2v d2 = pl32(c2[qh][2*kh][j], c2[qh][2*kh+1][j]);
          uint2v e2 = pl16(d2[0], d2[1]);
          u2[j] = e2[0]; u2[2+j] = e2[1];
        }
      }

    // ---- PV ----
    __builtin_amdgcn_s_setprio(1);
    #pragma unroll
    for (int kh=0; kh<2; ++kh){
      #pragma unroll
      for (int fd=0; fd<4; ++fd){
        bf16x8 vb = *(const bf16x8*)&Vs[(fd*16+q)*64 + ((kh*4+g)^sw)*8];
        #pragma unroll
        for (int qh=0; qh<2; ++qh){
          acc1[qh][fd] = __builtin_amdgcn_mfma_f32_16x16x32_bf16(pa1[qh][kh], vb, acc1[qh][fd], 0,0,0);
          acc2[qh][fd] = __builtin_amdgcn_mfma_f32_16x16x32_bf16(pa2[qh][kh], vb, acc2[qh][fd], 0,0,0);
        }
      }
    }
    __builtin_amdgcn_s_setprio(0);
  }

  // epilogue: denominators + combine
  float lamb = lambp[0];
  #pragma unroll
  for (int qh=0; qh<2; ++qh){
    float s1 = s1p[qh]; s1 += __shfl_xor(s1, 16); s1 += __shfl_xor(s1, 32);
    float s2 = s2p[qh]; s2 += __shfl_xor(s2, 16); s2 += __shfl_xor(s2, 32);
    float r1 = 1.0f/s1, r2 = lamb/s2;
    float inv1[4], inv2[4];
    #pragma unroll
    for (int i=0;i<4;i++){
      inv1[i] = __shfl(r1, g*4+i);
      inv2[i] = __shfl(r2, g*4+i);
    }
    #pragma unroll
    for (int fd=0; fd<4; ++fd)
      #pragma unroll
      for (int i=0;i<4;i++){
        float val = acc1[qh][fd][i]*inv1[i] - acc2[qh][fd][i]*inv2[i];
        int row = qrow0 + qh*16 + g*4 + i;
        int col = h*64 + fd*16 + q;
        aout[(size_t)row*1024 + col] = f2bf(val);
      }
  }
}

__global__ __launch_bounds__(256) void f32_to_bf16_k(const float* __restrict__ in, unsigned short* __restrict__ out, int n){
  int i = (blockIdx.x*256 + threadIdx.x)*4;
  if (i >= n) return;
  float4 vv = *(const float4*)(in + i);
  us4v o; o[0]=f2bf(vv.x); o[1]=f2bf(vv.y); o[2]=f2bf(vv.z); o[3]=f2bf(vv.w);
  *(us4v*)(out + i) = o;
}

// in: [R][C] f32 -> out: [C][R] bf16
__global__ void transpose_f32_bf16(const float* __restrict__ in, unsigned short* __restrict__ out, int R, int C){
  __shared__ unsigned short t[32][33];
  int c0 = blockIdx.x*32, r0 = blockIdx.y*32;
  int x = threadIdx.x, y = threadIdx.y;
  #pragma unroll
  for (int d=0; d<32; d+=8) t[y+d][x] = f2bf(in[(size_t)(r0+y+d)*C + c0 + x]);
  __syncthreads();
  #pragma unroll
  for (int d=0; d<32; d+=8) out[(size_t)(c0+y+d)*R + r0 + x] = t[x][y+d];
}

// in: [R][C] bf16 (row stride ldin) -> out: [C][R] bf16
__global__ void transpose_bf16_ld(const unsigned short* __restrict__ in, unsigned short* __restrict__ out, int R, int C, int ldin){
  __shared__ unsigned short t[32][33];
  int c0 = blockIdx.x*32, r0 = blockIdx.y*32;
  int x = threadIdx.x, y = threadIdx.y;
  #pragma unroll
  for (int d=0; d<32; d+=8) t[y+d][x] = in[(size_t)(r0+y+d)*ldin + c0 + x];
  __syncthreads();
  #pragma unroll
  for (int d=0; d<32; d+=8) out[(size_t)(c0+y+d)*R + r0 + x] = t[x][y+d];
}

__global__ void lamb_k(const float* lq1, const float* lk1, const float* lq2, const float* lk2, float* out){
  int i = threadIdx.x;
  float a = lq1[i]*lk1[i], c = lq2[i]*lk2[i];
  #pragma unroll
  for (int o=32;o>0;o>>=1){ a += __shfl_down(a,o); c += __shfl_down(c,o); }
  if (i==0) out[0] = expf(a) - expf(c) + 0.7778700995592560f; // LAMBDA_INIT for layer 12
}

__global__ __launch_bounds__(256) void ln_k(const float* __restrict__ in, const float* __restrict__ gam,
                                            const float* __restrict__ bet, float* __restrict__ out){
  int row = blockIdx.x, t = threadIdx.x;
  const float4* rp = (const float4*)(in + (size_t)row*1024);
  float4 v4 = rp[t];
  float s = v4.x+v4.y+v4.z+v4.w;
  float ss = v4.x*v4.x+v4.y*v4.y+v4.z*v4.z+v4.w*v4.w;
  #pragma unroll
  for (int o=1;o<64;o<<=1){ s += __shfl_xor(s,o); ss += __shfl_xor(ss,o); }
  __shared__ float red[8];
  int w = t>>6, l = t&63;
  if (l==0){ red[w]=s; red[4+w]=ss; }
  __syncthreads();
  s = red[0]+red[1]+red[2]+red[3];
  ss = red[4]+red[5]+red[6]+red[7];
  float mean = s*(1.0f/1024.0f);
  float var = ss*(1.0f/1024.0f) - mean*mean;
  float rstd = rsqrtf(var + 1e-5f);
  float4 gv = ((const float4*)gam)[t], bv = ((const float4*)bet)[t];
  float4 o;
  o.x = (v4.x-mean)*rstd*gv.x + bv.x;
  o.y = (v4.y-mean)*rstd*gv.y + bv.y;
  o.z = (v4.z-mean)*rstd*gv.z + bv.z;
  o.w = (v4.w-mean)*rstd*gv.w + bv.w;
  ((float4*)(out + (size_t)row*1024))[t] = o;
}

extern "C" void kernel_launch(void* const* d_in, const int* in_sizes, int n_in,
                              void* d_out, int out_size, void* d_ws, size_t ws_size,
                              hipStream_t stream) {
  const float* x     = (const float*)d_in[0];
  const float* Wq    = (const float*)d_in[1];
  const float* Wk    = (const float*)d_in[2];
  const float* Wv    = (const float*)d_in[3];
  const float* Wo    = (const float*)d_in[4];
  const float* lq1   = (const float*)d_in[5];
  const float* lk1   = (const float*)d_in[6];
  const float* lq2   = (const float*)d_in[7];
  const float* lk2   = (const float*)d_in[8];
  const float* gamma = (const float*)d_in[9];
  const float* beta  = (const float*)d_in[10];
  float* out = (float*)d_out;

  char* ws = (char*)d_ws;
  unsigned short* xb    = (unsigned short*)(ws);                   //  8,388,608 B
  unsigned short* WcatT = (unsigned short*)(ws + 8388608);         // 10,485,760  [5120][1024]
  unsigned short* WoT   = (unsigned short*)(ws + 18874368);        //  2,097,152
  unsigned short* QKV   = (unsigned short*)(ws + 20971520);        // 41,943,040  [4096][5120]
  unsigned short* Vtb   = (unsigned short*)(ws + 62914560);        //  8,388,608  [1024][4096]
  unsigned short* AOb   = (unsigned short*)(ws + 71303168);        //  8,388,608
  float*          proj  = (float*)(ws + 79691776);                 // 16,777,216
  float*          lambp = (float*)(ws + 96468992);                 //  4

  dim3 tb(32,8);
  f32_to_bf16_k<<<4096, 256, 0, stream>>>(x, xb, 4194304);
  transpose_f32_bf16<<<dim3(64,32), tb, 0, stream>>>(Wq, WcatT,             1024, 2048);
  transpose_f32_bf16<<<dim3(64,32), tb, 0, stream>>>(Wk, WcatT + 2048*1024, 1024, 2048);
  transpose_f32_bf16<<<dim3(32,32), tb, 0, stream>>>(Wv, WcatT + 4096*1024, 1024, 1024);
  transpose_f32_bf16<<<dim3(32,32), tb, 0, stream>>>(Wo, WoT, 1024, 1024);
  lamb_k<<<1, 64, 0, stream>>>(lq1, lk1, lq2, lk2, lambp);

  // fused QKV projection: [4096][1024] @ [5120][1024]^T -> [4096][5120]
  gemm_bt<unsigned short><<<dim3(32,40), 256, 0, stream>>>(xb, WcatT, QKV, 4096, 5120, 1024);
  // V^T from QKV cols 4096..5119
  transpose_bf16_ld<<<dim3(32,128), tb, 0, stream>>>(QKV + 4096, Vtb, 4096, 1024, 5120);

  diff_attn<<<dim3(16,16,2), 256, 0, stream>>>(QKV, QKV + 2048, Vtb, lambp, AOb);

  gemm_bt<float><<<dim3(32,8), 256, 0, stream>>>(AOb, WoT, proj, 4096, 1024, 1024);
  ln_k<<<4096, 256, 0, stream>>>(proj, gamma, beta, out);
}

// Round 8
// 242.026 us; speedup vs baseline: 3.0009x; 1.0185x over previous
//
#include <hip/hip_runtime.h>
#include <hip/hip_bf16.h>

typedef short bf16x8 __attribute__((ext_vector_type(8)));
typedef float f32x4 __attribute__((ext_vector_type(4)));
typedef unsigned short us4v __attribute__((ext_vector_type(4)));
typedef unsigned int uint2v __attribute__((ext_vector_type(2)));

#define DEV static __device__ __forceinline__

DEV float bf2f(unsigned short u){ unsigned int x = ((unsigned int)u)<<16; float f; __builtin_memcpy(&f,&x,4); return f; }
DEV unsigned short f2bf(float f){ unsigned int x; __builtin_memcpy(&x,&f,4); x = (x + 0x7fffu + ((x>>16)&1u)) >> 16; return (unsigned short)x; }
DEV unsigned int pack_bf16x2(float lo, float hi){
  __hip_bfloat162 h = __float22bfloat162_rn(float2{lo, hi});
  unsigned int u; __builtin_memcpy(&u, &h, 4); return u;
}

DEV void stor(unsigned short* p, float v){ *p = f2bf(v); }
DEV void stor(float* p, float v){ *p = v; }

#if __has_builtin(__builtin_amdgcn_permlane32_swap)
DEV uint2v pl32(unsigned int a, unsigned int b){ return __builtin_amdgcn_permlane32_swap(a, b, false, false); }
#else
DEV uint2v pl32(unsigned int a, unsigned int b){
  unsigned int sa = (unsigned int)__shfl_xor((int)a, 32);
  unsigned int sb = (unsigned int)__shfl_xor((int)b, 32);
  bool hi = (threadIdx.x & 32) != 0;
  uint2v r; r[0] = hi ? sb : a; r[1] = hi ? b : sa; return r;
}
#endif
#if __has_builtin(__builtin_amdgcn_permlane16_swap)
DEV uint2v pl16(unsigned int a, unsigned int b){ return __builtin_amdgcn_permlane16_swap(a, b, false, false); }
#else
DEV uint2v pl16(unsigned int a, unsigned int b){
  unsigned int sa = (unsigned int)__shfl_xor((int)a, 16);
  unsigned int sb = (unsigned int)__shfl_xor((int)b, 16);
  bool hi = (threadIdx.x & 16) != 0;
  uint2v r; r[0] = hi ? sb : a; r[1] = hi ? b : sa; return r;
}
#endif

#define GLOAD_LDS16(gptr, lptr) \
  __builtin_amdgcn_global_load_lds((__attribute__((address_space(1))) void*)(gptr), \
      (__attribute__((address_space(3))) void*)(lptr), 16, 0, 0)

// C = A[M,K] @ Bt[N,K]^T, bf16 inputs, OutT output. 128x128 tile, BK=32, 4 waves.
template<typename OutT>
__global__ __launch_bounds__(256) void gemm_bt(
    const unsigned short* __restrict__ A,
    const unsigned short* __restrict__ Bt,
    OutT* __restrict__ C, int M, int N, int K)
{
  __shared__ unsigned short As[128*32];
  __shared__ unsigned short Bs[128*32];
  const int tid = threadIdx.x;
  const int w = tid>>6, l = tid&63, g = l>>4, q = l&15;
  const int m0 = blockIdx.x*128, n0 = blockIdx.y*128;
  f32x4 acc[4][4];
  const f32x4 fz = {0.f,0.f,0.f,0.f};
  for (int i=0;i<4;i++) for(int j=0;j<4;j++) acc[i][j] = fz;
  for (int k0 = 0; k0 < K; k0 += 32) {
    __syncthreads();
    #pragma unroll
    for (int r = 0; r < 2; ++r) {
      int p = r*4096 + tid*16;
      int row = p>>6, colb = p&63;
      const char* ga = (const char*)(A  + (size_t)(m0+row)*K + k0) + colb;
      const char* gb = (const char*)(Bt + (size_t)(n0+row)*K + k0) + colb;
      GLOAD_LDS16(ga, (char*)As + r*4096 + w*1024);
      GLOAD_LDS16(gb, (char*)Bs + r*4096 + w*1024);
    }
    __syncthreads();
    bf16x8 af[4], bfr[4];
    #pragma unroll
    for (int i=0;i<4;i++){
      af[i]  = *(const bf16x8*)&As[((w>>1)*64 + i*16 + q)*32 + g*8];
      bfr[i] = *(const bf16x8*)&Bs[((w&1)*64 + i*16 + q)*32 + g*8];
    }
    #pragma unroll
    for (int i=0;i<4;i++)
      #pragma unroll
      for (int j=0;j<4;j++)
        acc[i][j] = __builtin_amdgcn_mfma_f32_16x16x32_bf16(af[i], bfr[j], acc[i][j], 0,0,0);
  }
  #pragma unroll
  for (int i=0;i<4;i++)
    #pragma unroll
    for (int j=0;j<4;j++)
      #pragma unroll
      for (int v=0;v<4;v++){
        int row = m0 + (w>>1)*64 + i*16 + g*4 + v;
        int col = n0 + (w&1)*64 + j*16 + q;
        stor(&C[(size_t)row*N + col], acc[i][j][v]);
      }
}

// Differential flash attention v8: v6 arithmetic (exp2f + RNE pack) +
// double-buffered LDS single barrier/tile + MFMA-ones denominators.
// Qp/Kp rows ld=5120 (merged QKV); Vt: [1024][4096]. aout: [4096][1024].
// Q pre-scaled by 0.125*log2(e) so p = exp2(z).
__global__ __launch_bounds__(256,2) void diff_attn(
    const unsigned short* __restrict__ Qp,
    const unsigned short* __restrict__ Kp,
    const unsigned short* __restrict__ Vt,
    const float* __restrict__ lambp,
    unsigned short* __restrict__ aout)
{
  const int LDQ = 5120;
  __shared__ unsigned short Ks[2][64*128];   // 32 KiB, granule ^ (row&7)
  __shared__ unsigned short Vs[2][64*64];    // 16 KiB, granule ^ (row&7) [d-major]
  const int tid = threadIdx.x, w = tid>>6, l = tid&63, g = l>>4, q = l&15;
  const int qb = blockIdx.x, h = blockIdx.y, b = blockIdx.z;
  const int qrow0 = b*2048 + qb*128 + w*32;
  const f32x4 fz = {0.f,0.f,0.f,0.f};
  const short one_bf = (short)0x3f80;
  const bf16x8 ones = {one_bf,one_bf,one_bf,one_bf,one_bf,one_bf,one_bf,one_bf};

  // Q fragments for 2 q-subtiles, scaled by (1/8)*log2(e)
  const float QSCALE = 0.125f * 1.4426950408889634f;
  bf16x8 q1f[2][2], q2f[2][2];
  #pragma unroll
  for (int qh=0; qh<2; ++qh){
    const unsigned short* qp = Qp + (size_t)(qrow0 + qh*16 + q)*LDQ + h*128;
    #pragma unroll
    for (int kf=0;kf<2;kf++){
      bf16x8 t1 = *(const bf16x8*)(qp + kf*32 + g*8);
      bf16x8 t2 = *(const bf16x8*)(qp + 64 + kf*32 + g*8);
      #pragma unroll
      for (int e=0;e<8;e++){
        t1[e] = (short)f2bf(bf2f((unsigned short)t1[e]) * QSCALE);
        t2[e] = (short)f2bf(bf2f((unsigned short)t2[e]) * QSCALE);
      }
      q1f[qh][kf]=t1; q2f[qh][kf]=t2;
    }
  }
  f32x4 acc1[2][4], acc2[2][4];
  f32x4 acc_s1[2], acc_s2[2];   // denominators via P @ ones
  #pragma unroll
  for (int qh=0;qh<2;qh++){
    acc_s1[qh]=fz; acc_s2[qh]=fz;
    #pragma unroll
    for (int i=0;i<4;i++){ acc1[qh][i]=fz; acc2[qh][i]=fz; }
  }

  const int rowl = l;
  const int swl = rowl & 7;
  const unsigned short* pK = Kp + (size_t)(b*2048 + rowl)*LDQ + h*128;
  const unsigned short* pV = Vt + (size_t)(h*64 + rowl)*4096 + b*2048;

  bf16x8 kreg[4], vreg[2];
  auto LOADT = [&](){
    #pragma unroll
    for (int c=0;c<4;c++) kreg[c] = *(const bf16x8*)(pK + (w + c*4)*8);
    #pragma unroll
    for (int c=0;c<2;c++) vreg[c] = *(const bf16x8*)(pV + (w + c*4)*8);
    pK += (size_t)64*LDQ;
    pV += 64;
  };
  auto WRITET = [&](int bb){
    #pragma unroll
    for (int c=0;c<4;c++){
      int ch = w + c*4;
      *(bf16x8*)&Ks[bb][rowl*128 + (ch^swl)*8] = kreg[c];
    }
    #pragma unroll
    for (int c=0;c<2;c++){
      int ch = w + c*4;
      *(bf16x8*)&Vs[bb][rowl*64 + (ch^swl)*8] = vreg[c];
    }
  };

  LOADT();          // tile 0 -> regs
  WRITET(0);        // commit tile 0
  __syncthreads();

  for (int t=0; t<32; ++t) {
    const int bb = t & 1;
    if (t < 31) LOADT();     // next tile's global loads land during compute
    const int sw = q & 7;

    // ---- swapped QK^T: per qh, z[fn] = C[key=fn*16+g*4+i][qrow] ----
    unsigned int c1[2][4][2], c2[2][4][2];
    #pragma unroll
    for (int fn=0; fn<4; ++fn) {
      const unsigned short* kr = &Ks[bb][(fn*16 + q)*128];
      bf16x8 kb0 = *(const bf16x8*)&kr[((0+g)^sw)*8];
      bf16x8 kb1 = *(const bf16x8*)&kr[((4+g)^sw)*8];
      bf16x8 kc0 = *(const bf16x8*)&kr[((8+g)^sw)*8];
      bf16x8 kc1 = *(const bf16x8*)&kr[((12+g)^sw)*8];
      f32x4 za[2], zc[2];
      __builtin_amdgcn_s_setprio(1);
      #pragma unroll
      for (int qh=0; qh<2; ++qh){
        f32x4 a = fz, c = fz;
        a = __builtin_amdgcn_mfma_f32_16x16x32_bf16(kb0, q1f[qh][0], a, 0,0,0);
        a = __builtin_amdgcn_mfma_f32_16x16x32_bf16(kb1, q1f[qh][1], a, 0,0,0);
        c = __builtin_amdgcn_mfma_f32_16x16x32_bf16(kc0, q2f[qh][0], c, 0,0,0);
        c = __builtin_amdgcn_mfma_f32_16x16x32_bf16(kc1, q2f[qh][1], c, 0,0,0);
        za[qh]=a; zc[qh]=c;
      }
      __builtin_amdgcn_s_setprio(0);
      #pragma unroll
      for (int qh=0; qh<2; ++qh){
        float e0 = exp2f(za[qh][0]), e1 = exp2f(za[qh][1]);
        float e2 = exp2f(za[qh][2]), e3 = exp2f(za[qh][3]);
        c1[qh][fn][0] = pack_bf16x2(e0,e1); c1[qh][fn][1] = pack_bf16x2(e2,e3);
        float f0 = exp2f(zc[qh][0]), f1 = exp2f(zc[qh][1]);
        float f2 = exp2f(zc[qh][2]), f3 = exp2f(zc[qh][3]);
        c2[qh][fn][0] = pack_bf16x2(f0,f1); c2[qh][fn][1] = pack_bf16x2(f2,f3);
      }
    }

    // ---- in-register P -> A-frag via permlane swaps (per qh) ----
    bf16x8 pa1[2][2], pa2[2][2];
    #pragma unroll
    for (int qh=0; qh<2; ++qh)
      #pragma unroll
      for (int kh=0; kh<2; ++kh){
        unsigned int* u1 = (unsigned int*)&pa1[qh][kh];
        unsigned int* u2 = (unsigned int*)&pa2[qh][kh];
        #pragma unroll
        for (int j=0;j<2;j++){
          uint2v d = pl32(c1[qh][2*kh][j], c1[qh][2*kh+1][j]);
          uint2v e = pl16(d[0], d[1]);
          u1[j] = e[0]; u1[2+j] = e[1];
          uint2v d2 = pl32(c2[qh][2*kh][j], c2[qh][2*kh+1][j]);
          uint2v e2 = pl16(d2[0], d2[1]);
          u2[j] = e2[0]; u2[2+j] = e2[1];
        }
      }

    // ---- PV + denominator MFMAs ----
    __builtin_amdgcn_s_setprio(1);
    #pragma unroll
    for (int kh=0; kh<2; ++kh){
      #pragma unroll
      for (int qh=0; qh<2; ++qh){
        acc_s1[qh] = __builtin_amdgcn_mfma_f32_16x16x32_bf16(pa1[qh][kh], ones, acc_s1[qh], 0,0,0);
        acc_s2[qh] = __builtin_amdgcn_mfma_f32_16x16x32_bf16(pa2[qh][kh], ones, acc_s2[qh], 0,0,0);
      }
      #pragma unroll
      for (int fd=0; fd<4; ++fd){
        bf16x8 vb = *(const bf16x8*)&Vs[bb][(fd*16+q)*64 + ((kh*4+g)^sw)*8];
        #pragma unroll
        for (int qh=0; qh<2; ++qh){
          acc1[qh][fd] = __builtin_amdgcn_mfma_f32_16x16x32_bf16(pa1[qh][kh], vb, acc1[qh][fd], 0,0,0);
          acc2[qh][fd] = __builtin_amdgcn_mfma_f32_16x16x32_bf16(pa2[qh][kh], vb, acc2[qh][fd], 0,0,0);
        }
      }
    }
    __builtin_amdgcn_s_setprio(0);

    if (t < 31){
      WRITET((t+1)&1);        // other buffer: all waves done reading it
      __syncthreads();        // single barrier per tile
    }
  }

  // epilogue: acc_s[i] = s[qrow=g*4+i] (all lanes), layout-aligned with acc1
  float lamb = lambp[0];
  #pragma unroll
  for (int qh=0; qh<2; ++qh){
    float inv1[4], inv2[4];
    #pragma unroll
    for (int i=0;i<4;i++){
      inv1[i] = 1.0f/acc_s1[qh][i];
      inv2[i] = lamb/acc_s2[qh][i];
    }
    #pragma unroll
    for (int fd=0; fd<4; ++fd)
      #pragma unroll
      for (int i=0;i<4;i++){
        float val = acc1[qh][fd][i]*inv1[i] - acc2[qh][fd][i]*inv2[i];
        int row = qrow0 + qh*16 + g*4 + i;
        int col = h*64 + fd*16 + q;
        aout[(size_t)row*1024 + col] = f2bf(val);
      }
  }
}

__global__ __launch_bounds__(256) void f32_to_bf16_k(const float* __restrict__ in, unsigned short* __restrict__ out, int n){
  int i = (blockIdx.x*256 + threadIdx.x)*4;
  if (i >= n) return;
  float4 vv = *(const float4*)(in + i);
  us4v o; o[0]=f2bf(vv.x); o[1]=f2bf(vv.y); o[2]=f2bf(vv.z); o[3]=f2bf(vv.w);
  *(us4v*)(out + i) = o;
}

// in: [R][C] f32 -> out: [C][R] bf16
__global__ void transpose_f32_bf16(const float* __restrict__ in, unsigned short* __restrict__ out, int R, int C){
  __shared__ unsigned short t[32][33];
  int c0 = blockIdx.x*32, r0 = blockIdx.y*32;
  int x = threadIdx.x, y = threadIdx.y;
  #pragma unroll
  for (int d=0; d<32; d+=8) t[y+d][x] = f2bf(in[(size_t)(r0+y+d)*C + c0 + x]);
  __syncthreads();
  #pragma unroll
  for (int d=0; d<32; d+=8) out[(size_t)(c0+y+d)*R + r0 + x] = t[x][y+d];
}

// in: [R][C] bf16 (row stride ldin) -> out: [C][R] bf16
__global__ void transpose_bf16_ld(const unsigned short* __restrict__ in, unsigned short* __restrict__ out, int R, int C, int ldin){
  __shared__ unsigned short t[32][33];
  int c0 = blockIdx.x*32, r0 = blockIdx.y*32;
  int x = threadIdx.x, y = threadIdx.y;
  #pragma unroll
  for (int d=0; d<32; d+=8) t[y+d][x] = in[(size_t)(r0+y+d)*ldin + c0 + x];
  __syncthreads();
  #pragma unroll
  for (int d=0; d<32; d+=8) out[(size_t)(c0+y+d)*R + r0 + x] = t[x][y+d];
}

__global__ void lamb_k(const float* lq1, const float* lk1, const float* lq2, const float* lk2, float* out){
  int i = threadIdx.x;
  float a = lq1[i]*lk1[i], c = lq2[i]*lk2[i];
  #pragma unroll
  for (int o=32;o>0;o>>=1){ a += __shfl_down(a,o); c += __shfl_down(c,o); }
  if (i==0) out[0] = expf(a) - expf(c) + 0.7778700995592560f; // LAMBDA_INIT for layer 12
}

__global__ __launch_bounds__(256) void ln_k(const float* __restrict__ in, const float* __restrict__ gam,
                                            const float* __restrict__ bet, float* __restrict__ out){
  int row = blockIdx.x, t = threadIdx.x;
  const float4* rp = (const float4*)(in + (size_t)row*1024);
  float4 v4 = rp[t];
  float s = v4.x+v4.y+v4.z+v4.w;
  float ss = v4.x*v4.x+v4.y*v4.y+v4.z*v4.z+v4.w*v4.w;
  #pragma unroll
  for (int o=1;o<64;o<<=1){ s += __shfl_xor(s,o); ss += __shfl_xor(ss,o); }
  __shared__ float red[8];
  int w = t>>6, l = t&63;
  if (l==0){ red[w]=s; red[4+w]=ss; }
  __syncthreads();
  s = red[0]+red[1]+red[2]+red[3];
  ss = red[4]+red[5]+red[6]+red[7];
  float mean = s*(1.0f/1024.0f);
  float var = ss*(1.0f/1024.0f) - mean*mean;
  float rstd = rsqrtf(var + 1e-5f);
  float4 gv = ((const float4*)gam)[t], bv = ((const float4*)bet)[t];
  float4 o;
  o.x = (v4.x-mean)*rstd*gv.x + bv.x;
  o.y = (v4.y-mean)*rstd*gv.y + bv.y;
  o.z = (v4.z-mean)*rstd*gv.z + bv.z;
  o.w = (v4.w-mean)*rstd*gv.w + bv.w;
  ((float4*)(out + (size_t)row*1024))[t] = o;
}

extern "C" void kernel_launch(void* const* d_in, const int* in_sizes, int n_in,
                              void* d_out, int out_size, void* d_ws, size_t ws_size,
                              hipStream_t stream) {
  const float* x     = (const float*)d_in[0];
  const float* Wq    = (const float*)d_in[1];
  const float* Wk    = (const float*)d_in[2];
  const float* Wv    = (const float*)d_in[3];
  const float* Wo    = (const float*)d_in[4];
  const float* lq1   = (const float*)d_in[5];
  const float* lk1   = (const float*)d_in[6];
  const float* lq2   = (const float*)d_in[7];
  const float* lk2   = (const float*)d_in[8];
  const float* gamma = (const float*)d_in[9];
  const float* beta  = (const float*)d_in[10];
  float* out = (float*)d_out;

  char* ws = (char*)d_ws;
  unsigned short* xb    = (unsigned short*)(ws);                   //  8,388,608 B
  unsigned short* WcatT = (unsigned short*)(ws + 8388608);         // 10,485,760  [5120][1024]
  unsigned short* WoT   = (unsigned short*)(ws + 18874368);        //  2,097,152
  unsigned short* QKV   = (unsigned short*)(ws + 20971520);        // 41,943,040  [4096][5120]
  unsigned short* Vtb   = (unsigned short*)(ws + 62914560);        //  8,388,608  [1024][4096]
  unsigned short* AOb   = (unsigned short*)(ws + 71303168);        //  8,388,608
  float*          proj  = (float*)(ws + 79691776);                 // 16,777,216
  float*          lambp = (float*)(ws + 96468992);                 //  4

  dim3 tb(32,8);
  f32_to_bf16_k<<<4096, 256, 0, stream>>>(x, xb, 4194304);
  transpose_f32_bf16<<<dim3(64,32), tb, 0, stream>>>(Wq, WcatT,             1024, 2048);
  transpose_f32_bf16<<<dim3(64,32), tb, 0, stream>>>(Wk, WcatT + 2048*1024, 1024, 2048);
  transpose_f32_bf16<<<dim3(32,32), tb, 0, stream>>>(Wv, WcatT + 4096*1024, 1024, 1024);
  transpose_f32_bf16<<<dim3(32,32), tb, 0, stream>>>(Wo, WoT, 1024, 1024);
  lamb_k<<<1, 64, 0, stream>>>(lq1, lk1, lq2, lk2, lambp);

  // fused QKV projection: [4096][1024] @ [5120][1024]^T -> [4096][5120]
  gemm_bt<unsigned short><<<dim3(32,40), 256, 0, stream>>>(xb, WcatT, QKV, 4096, 5120, 1024);
  // V^T from QKV cols 4096..5119
  transpose_bf16_ld<<<dim3(32,128), tb, 0, stream>>>(QKV + 4096, Vtb, 4096, 1024, 5120);

  diff_attn<<<dim3(16,16,2), 256, 0, stream>>>(QKV, QKV + 2048, Vtb, lambp, AOb);

  gemm_bt<float><<<dim3(32,8), 256, 0, stream>>>(AOb, WoT, proj, 4096, 1024, 1024);
  ln_k<<<4096, 256, 0, stream>>>(proj, gamma, beta, out);
}

// Round 9
// 231.136 us; speedup vs baseline: 3.1423x; 1.0471x over previous
//
#include <hip/hip_runtime.h>
#include <hip/hip_bf16.h>

typedef short bf16x8 __attribute__((ext_vector_type(8)));
typedef float f32x4 __attribute__((ext_vector_type(4)));
typedef unsigned short us4v __attribute__((ext_vector_type(4)));
typedef unsigned int uint2v __attribute__((ext_vector_type(2)));

#define DEV static __device__ __forceinline__

DEV float bf2f(unsigned short u){ unsigned int x = ((unsigned int)u)<<16; float f; __builtin_memcpy(&f,&x,4); return f; }
DEV unsigned short f2bf(float f){ unsigned int x; __builtin_memcpy(&x,&f,4); x = (x + 0x7fffu + ((x>>16)&1u)) >> 16; return (unsigned short)x; }

// truncation pack: bf16(lo) | bf16(hi)<<16, round-toward-zero (3 VALU ops).
// Numerator/denominator consistency is preserved (both consume these bits).
DEV unsigned int pack_trunc(float lo, float hi){
  unsigned int a, b;
  __builtin_memcpy(&a, &lo, 4);
  __builtin_memcpy(&b, &hi, 4);
  return (b & 0xffff0000u) | (a >> 16);
}

DEV void stor(unsigned short* p, float v){ *p = f2bf(v); }
DEV void stor(float* p, float v){ *p = v; }

#if __has_builtin(__builtin_amdgcn_permlane32_swap)
DEV uint2v pl32(unsigned int a, unsigned int b){ return __builtin_amdgcn_permlane32_swap(a, b, false, false); }
#else
DEV uint2v pl32(unsigned int a, unsigned int b){
  unsigned int sa = (unsigned int)__shfl_xor((int)a, 32);
  unsigned int sb = (unsigned int)__shfl_xor((int)b, 32);
  bool hi = (threadIdx.x & 32) != 0;
  uint2v r; r[0] = hi ? sb : a; r[1] = hi ? b : sa; return r;
}
#endif
#if __has_builtin(__builtin_amdgcn_permlane16_swap)
DEV uint2v pl16(unsigned int a, unsigned int b){ return __builtin_amdgcn_permlane16_swap(a, b, false, false); }
#else
DEV uint2v pl16(unsigned int a, unsigned int b){
  unsigned int sa = (unsigned int)__shfl_xor((int)a, 16);
  unsigned int sb = (unsigned int)__shfl_xor((int)b, 16);
  bool hi = (threadIdx.x & 16) != 0;
  uint2v r; r[0] = hi ? sb : a; r[1] = hi ? b : sa; return r;
}
#endif

#define GLOAD_LDS16(gptr, lptr) \
  __builtin_amdgcn_global_load_lds((__attribute__((address_space(1))) void*)(gptr), \
      (__attribute__((address_space(3))) void*)(lptr), 16, 0, 0)

// C = A[M,K] @ Bt[N,K]^T, bf16 inputs, OutT output. 128x128 tile, BK=32, 4 waves.
template<typename OutT>
__global__ __launch_bounds__(256) void gemm_bt(
    const unsigned short* __restrict__ A,
    const unsigned short* __restrict__ Bt,
    OutT* __restrict__ C, int M, int N, int K)
{
  __shared__ unsigned short As[128*32];
  __shared__ unsigned short Bs[128*32];
  const int tid = threadIdx.x;
  const int w = tid>>6, l = tid&63, g = l>>4, q = l&15;
  const int m0 = blockIdx.x*128, n0 = blockIdx.y*128;
  f32x4 acc[4][4];
  const f32x4 fz = {0.f,0.f,0.f,0.f};
  for (int i=0;i<4;i++) for(int j=0;j<4;j++) acc[i][j] = fz;
  for (int k0 = 0; k0 < K; k0 += 32) {
    __syncthreads();
    #pragma unroll
    for (int r = 0; r < 2; ++r) {
      int p = r*4096 + tid*16;
      int row = p>>6, colb = p&63;
      const char* ga = (const char*)(A  + (size_t)(m0+row)*K + k0) + colb;
      const char* gb = (const char*)(Bt + (size_t)(n0+row)*K + k0) + colb;
      GLOAD_LDS16(ga, (char*)As + r*4096 + w*1024);
      GLOAD_LDS16(gb, (char*)Bs + r*4096 + w*1024);
    }
    __syncthreads();
    bf16x8 af[4], bfr[4];
    #pragma unroll
    for (int i=0;i<4;i++){
      af[i]  = *(const bf16x8*)&As[((w>>1)*64 + i*16 + q)*32 + g*8];
      bfr[i] = *(const bf16x8*)&Bs[((w&1)*64 + i*16 + q)*32 + g*8];
    }
    #pragma unroll
    for (int i=0;i<4;i++)
      #pragma unroll
      for (int j=0;j<4;j++)
        acc[i][j] = __builtin_amdgcn_mfma_f32_16x16x32_bf16(af[i], bfr[j], acc[i][j], 0,0,0);
  }
  #pragma unroll
  for (int i=0;i<4;i++)
    #pragma unroll
    for (int j=0;j<4;j++)
      #pragma unroll
      for (int v=0;v<4;v++){
        int row = m0 + (w>>1)*64 + i*16 + g*4 + v;
        int col = n0 + (w&1)*64 + j*16 + q;
        stor(&C[(size_t)row*N + col], acc[i][j][v]);
      }
}

// Differential flash attention v9: v8 structure (double-buffered LDS, single
// barrier/tile, MFMA-ones denominators) with truncation bf16 pack (3 VALU ops).
// Qp/Kp rows ld=5120 (merged QKV); Vt: [1024][4096]. aout: [4096][1024].
// Q pre-scaled by 0.125*log2(e) so p = exp2(z).
__global__ __launch_bounds__(256,2) void diff_attn(
    const unsigned short* __restrict__ Qp,
    const unsigned short* __restrict__ Kp,
    const unsigned short* __restrict__ Vt,
    const float* __restrict__ lambp,
    unsigned short* __restrict__ aout)
{
  const int LDQ = 5120;
  __shared__ unsigned short Ks[2][64*128];   // 32 KiB, granule ^ (row&7)
  __shared__ unsigned short Vs[2][64*64];    // 16 KiB, granule ^ (row&7) [d-major]
  const int tid = threadIdx.x, w = tid>>6, l = tid&63, g = l>>4, q = l&15;
  const int qb = blockIdx.x, h = blockIdx.y, b = blockIdx.z;
  const int qrow0 = b*2048 + qb*128 + w*32;
  const f32x4 fz = {0.f,0.f,0.f,0.f};
  const short one_bf = (short)0x3f80;
  const bf16x8 ones = {one_bf,one_bf,one_bf,one_bf,one_bf,one_bf,one_bf,one_bf};

  // Q fragments for 2 q-subtiles, scaled by (1/8)*log2(e)
  const float QSCALE = 0.125f * 1.4426950408889634f;
  bf16x8 q1f[2][2], q2f[2][2];
  #pragma unroll
  for (int qh=0; qh<2; ++qh){
    const unsigned short* qp = Qp + (size_t)(qrow0 + qh*16 + q)*LDQ + h*128;
    #pragma unroll
    for (int kf=0;kf<2;kf++){
      bf16x8 t1 = *(const bf16x8*)(qp + kf*32 + g*8);
      bf16x8 t2 = *(const bf16x8*)(qp + 64 + kf*32 + g*8);
      #pragma unroll
      for (int e=0;e<8;e++){
        t1[e] = (short)f2bf(bf2f((unsigned short)t1[e]) * QSCALE);
        t2[e] = (short)f2bf(bf2f((unsigned short)t2[e]) * QSCALE);
      }
      q1f[qh][kf]=t1; q2f[qh][kf]=t2;
    }
  }
  f32x4 acc1[2][4], acc2[2][4];
  f32x4 acc_s1[2], acc_s2[2];   // denominators via P @ ones
  #pragma unroll
  for (int qh=0;qh<2;qh++){
    acc_s1[qh]=fz; acc_s2[qh]=fz;
    #pragma unroll
    for (int i=0;i<4;i++){ acc1[qh][i]=fz; acc2[qh][i]=fz; }
  }

  const int rowl = l;
  const int swl = rowl & 7;
  const unsigned short* pK = Kp + (size_t)(b*2048 + rowl)*LDQ + h*128;
  const unsigned short* pV = Vt + (size_t)(h*64 + rowl)*4096 + b*2048;

  bf16x8 kreg[4], vreg[2];
  auto LOADT = [&](){
    #pragma unroll
    for (int c=0;c<4;c++) kreg[c] = *(const bf16x8*)(pK + (w + c*4)*8);
    #pragma unroll
    for (int c=0;c<2;c++) vreg[c] = *(const bf16x8*)(pV + (w + c*4)*8);
    pK += (size_t)64*LDQ;
    pV += 64;
  };
  auto WRITET = [&](int bb){
    #pragma unroll
    for (int c=0;c<4;c++){
      int ch = w + c*4;
      *(bf16x8*)&Ks[bb][rowl*128 + (ch^swl)*8] = kreg[c];
    }
    #pragma unroll
    for (int c=0;c<2;c++){
      int ch = w + c*4;
      *(bf16x8*)&Vs[bb][rowl*64 + (ch^swl)*8] = vreg[c];
    }
  };

  LOADT();          // tile 0 -> regs
  WRITET(0);        // commit tile 0
  __syncthreads();

  for (int t=0; t<32; ++t) {
    const int bb = t & 1;
    if (t < 31) LOADT();     // next tile's global loads land during compute
    const int sw = q & 7;

    // ---- swapped QK^T: per qh, z[fn] = C[key=fn*16+g*4+i][qrow] ----
    unsigned int c1[2][4][2], c2[2][4][2];
    #pragma unroll
    for (int fn=0; fn<4; ++fn) {
      const unsigned short* kr = &Ks[bb][(fn*16 + q)*128];
      bf16x8 kb0 = *(const bf16x8*)&kr[((0+g)^sw)*8];
      bf16x8 kb1 = *(const bf16x8*)&kr[((4+g)^sw)*8];
      bf16x8 kc0 = *(const bf16x8*)&kr[((8+g)^sw)*8];
      bf16x8 kc1 = *(const bf16x8*)&kr[((12+g)^sw)*8];
      f32x4 za[2], zc[2];
      __builtin_amdgcn_s_setprio(1);
      #pragma unroll
      for (int qh=0; qh<2; ++qh){
        f32x4 a = fz, c = fz;
        a = __builtin_amdgcn_mfma_f32_16x16x32_bf16(kb0, q1f[qh][0], a, 0,0,0);
        a = __builtin_amdgcn_mfma_f32_16x16x32_bf16(kb1, q1f[qh][1], a, 0,0,0);
        c = __builtin_amdgcn_mfma_f32_16x16x32_bf16(kc0, q2f[qh][0], c, 0,0,0);
        c = __builtin_amdgcn_mfma_f32_16x16x32_bf16(kc1, q2f[qh][1], c, 0,0,0);
        za[qh]=a; zc[qh]=c;
      }
      __builtin_amdgcn_s_setprio(0);
      #pragma unroll
      for (int qh=0; qh<2; ++qh){
        float e0 = exp2f(za[qh][0]), e1 = exp2f(za[qh][1]);
        float e2 = exp2f(za[qh][2]), e3 = exp2f(za[qh][3]);
        c1[qh][fn][0] = pack_trunc(e0,e1); c1[qh][fn][1] = pack_trunc(e2,e3);
        float f0 = exp2f(zc[qh][0]), f1 = exp2f(zc[qh][1]);
        float f2 = exp2f(zc[qh][2]), f3 = exp2f(zc[qh][3]);
        c2[qh][fn][0] = pack_trunc(f0,f1); c2[qh][fn][1] = pack_trunc(f2,f3);
      }
    }

    // ---- in-register P -> A-frag via permlane swaps (per qh) ----
    bf16x8 pa1[2][2], pa2[2][2];
    #pragma unroll
    for (int qh=0; qh<2; ++qh)
      #pragma unroll
      for (int kh=0; kh<2; ++kh){
        unsigned int* u1 = (unsigned int*)&pa1[qh][kh];
        unsigned int* u2 = (unsigned int*)&pa2[qh][kh];
        #pragma unroll
        for (int j=0;j<2;j++){
          uint2v d = pl32(c1[qh][2*kh][j], c1[qh][2*kh+1][j]);
          uint2v e = pl16(d[0], d[1]);
          u1[j] = e[0]; u1[2+j] = e[1];
          uint2v d2 = pl32(c2[qh][2*kh][j], c2[qh][2*kh+1][j]);
          uint2v e2 = pl16(d2[0], d2[1]);
          u2[j] = e2[0]; u2[2+j] = e2[1];
        }
      }

    // ---- PV + denominator MFMAs ----
    __builtin_amdgcn_s_setprio(1);
    #pragma unroll
    for (int kh=0; kh<2; ++kh){
      #pragma unroll
      for (int qh=0; qh<2; ++qh){
        acc_s1[qh] = __builtin_amdgcn_mfma_f32_16x16x32_bf16(pa1[qh][kh], ones, acc_s1[qh], 0,0,0);
        acc_s2[qh] = __builtin_amdgcn_mfma_f32_16x16x32_bf16(pa2[qh][kh], ones, acc_s2[qh], 0,0,0);
      }
      #pragma unroll
      for (int fd=0; fd<4; ++fd){
        bf16x8 vb = *(const bf16x8*)&Vs[bb][(fd*16+q)*64 + ((kh*4+g)^sw)*8];
        #pragma unroll
        for (int qh=0; qh<2; ++qh){
          acc1[qh][fd] = __builtin_amdgcn_mfma_f32_16x16x32_bf16(pa1[qh][kh], vb, acc1[qh][fd], 0,0,0);
          acc2[qh][fd] = __builtin_amdgcn_mfma_f32_16x16x32_bf16(pa2[qh][kh], vb, acc2[qh][fd], 0,0,0);
        }
      }
    }
    __builtin_amdgcn_s_setprio(0);

    if (t < 31){
      WRITET((t+1)&1);        // other buffer: all waves done reading it
      __syncthreads();        // single barrier per tile
    }
  }

  // epilogue: acc_s[i] = s[qrow=g*4+i] (all lanes), layout-aligned with acc1
  float lamb = lambp[0];
  #pragma unroll
  for (int qh=0; qh<2; ++qh){
    float inv1[4], inv2[4];
    #pragma unroll
    for (int i=0;i<4;i++){
      inv1[i] = 1.0f/acc_s1[qh][i];
      inv2[i] = lamb/acc_s2[qh][i];
    }
    #pragma unroll
    for (int fd=0; fd<4; ++fd)
      #pragma unroll
      for (int i=0;i<4;i++){
        float val = acc1[qh][fd][i]*inv1[i] - acc2[qh][fd][i]*inv2[i];
        int row = qrow0 + qh*16 + g*4 + i;
        int col = h*64 + fd*16 + q;
        aout[(size_t)row*1024 + col] = f2bf(val);
      }
  }
}

__global__ __launch_bounds__(256) void f32_to_bf16_k(const float* __restrict__ in, unsigned short* __restrict__ out, int n){
  int i = (blockIdx.x*256 + threadIdx.x)*4;
  if (i >= n) return;
  float4 vv = *(const float4*)(in + i);
  us4v o; o[0]=f2bf(vv.x); o[1]=f2bf(vv.y); o[2]=f2bf(vv.z); o[3]=f2bf(vv.w);
  *(us4v*)(out + i) = o;
}

// in: [R][C] f32 -> out: [C][R] bf16
__global__ void transpose_f32_bf16(const float* __restrict__ in, unsigned short* __restrict__ out, int R, int C){
  __shared__ unsigned short t[32][33];
  int c0 = blockIdx.x*32, r0 = blockIdx.y*32;
  int x = threadIdx.x, y = threadIdx.y;
  #pragma unroll
  for (int d=0; d<32; d+=8) t[y+d][x] = f2bf(in[(size_t)(r0+y+d)*C + c0 + x]);
  __syncthreads();
  #pragma unroll
  for (int d=0; d<32; d+=8) out[(size_t)(c0+y+d)*R + r0 + x] = t[x][y+d];
}

// in: [R][C] bf16 (row stride ldin) -> out: [C][R] bf16
__global__ void transpose_bf16_ld(const unsigned short* __restrict__ in, unsigned short* __restrict__ out, int R, int C, int ldin){
  __shared__ unsigned short t[32][33];
  int c0 = blockIdx.x*32, r0 = blockIdx.y*32;
  int x = threadIdx.x, y = threadIdx.y;
  #pragma unroll
  for (int d=0; d<32; d+=8) t[y+d][x] = in[(size_t)(r0+y+d)*ldin + c0 + x];
  __syncthreads();
  #pragma unroll
  for (int d=0; d<32; d+=8) out[(size_t)(c0+y+d)*R + r0 + x] = t[x][y+d];
}

__global__ void lamb_k(const float* lq1, const float* lk1, const float* lq2, const float* lk2, float* out){
  int i = threadIdx.x;
  float a = lq1[i]*lk1[i], c = lq2[i]*lk2[i];
  #pragma unroll
  for (int o=32;o>0;o>>=1){ a += __shfl_down(a,o); c += __shfl_down(c,o); }
  if (i==0) out[0] = expf(a) - expf(c) + 0.7778700995592560f; // LAMBDA_INIT for layer 12
}

__global__ __launch_bounds__(256) void ln_k(const float* __restrict__ in, const float* __restrict__ gam,
                                            const float* __restrict__ bet, float* __restrict__ out){
  int row = blockIdx.x, t = threadIdx.x;
  const float4* rp = (const float4*)(in + (size_t)row*1024);
  float4 v4 = rp[t];
  float s = v4.x+v4.y+v4.z+v4.w;
  float ss = v4.x*v4.x+v4.y*v4.y+v4.z*v4.z+v4.w*v4.w;
  #pragma unroll
  for (int o=1;o<64;o<<=1){ s += __shfl_xor(s,o); ss += __shfl_xor(ss,o); }
  __shared__ float red[8];
  int w = t>>6, l = t&63;
  if (l==0){ red[w]=s; red[4+w]=ss; }
  __syncthreads();
  s = red[0]+red[1]+red[2]+red[3];
  ss = red[4]+red[5]+red[6]+red[7];
  float mean = s*(1.0f/1024.0f);
  float var = ss*(1.0f/1024.0f) - mean*mean;
  float rstd = rsqrtf(var + 1e-5f);
  float4 gv = ((const float4*)gam)[t], bv = ((const float4*)bet)[t];
  float4 o;
  o.x = (v4.x-mean)*rstd*gv.x + bv.x;
  o.y = (v4.y-mean)*rstd*gv.y + bv.y;
  o.z = (v4.z-mean)*rstd*gv.z + bv.z;
  o.w = (v4.w-mean)*rstd*gv.w + bv.w;
  ((float4*)(out + (size_t)row*1024))[t] = o;
}

extern "C" void kernel_launch(void* const* d_in, const int* in_sizes, int n_in,
                              void* d_out, int out_size, void* d_ws, size_t ws_size,
                              hipStream_t stream) {
  const float* x     = (const float*)d_in[0];
  const float* Wq    = (const float*)d_in[1];
  const float* Wk    = (const float*)d_in[2];
  const float* Wv    = (const float*)d_in[3];
  const float* Wo    = (const float*)d_in[4];
  const float* lq1   = (const float*)d_in[5];
  const float* lk1   = (const float*)d_in[6];
  const float* lq2   = (const float*)d_in[7];
  const float* lk2   = (const float*)d_in[8];
  const float* gamma = (const float*)d_in[9];
  const float* beta  = (const float*)d_in[10];
  float* out = (float*)d_out;

  char* ws = (char*)d_ws;
  unsigned short* xb    = (unsigned short*)(ws);                   //  8,388,608 B
  unsigned short* WcatT = (unsigned short*)(ws + 8388608);         // 10,485,760  [5120][1024]
  unsigned short* WoT   = (unsigned short*)(ws + 18874368);        //  2,097,152
  unsigned short* QKV   = (unsigned short*)(ws + 20971520);        // 41,943,040  [4096][5120]
  unsigned short* Vtb   = (unsigned short*)(ws + 62914560);        //  8,388,608  [1024][4096]
  unsigned short* AOb   = (unsigned short*)(ws + 71303168);        //  8,388,608
  float*          proj  = (float*)(ws + 79691776);                 // 16,777,216
  float*          lambp = (float*)(ws + 96468992);                 //  4

  dim3 tb(32,8);
  f32_to_bf16_k<<<4096, 256, 0, stream>>>(x, xb, 4194304);
  transpose_f32_bf16<<<dim3(64,32), tb, 0, stream>>>(Wq, WcatT,             1024, 2048);
  transpose_f32_bf16<<<dim3(64,32), tb, 0, stream>>>(Wk, WcatT + 2048*1024, 1024, 2048);
  transpose_f32_bf16<<<dim3(32,32), tb, 0, stream>>>(Wv, WcatT + 4096*1024, 1024, 1024);
  transpose_f32_bf16<<<dim3(32,32), tb, 0, stream>>>(Wo, WoT, 1024, 1024);
  lamb_k<<<1, 64, 0, stream>>>(lq1, lk1, lq2, lk2, lambp);

  // fused QKV projection: [4096][1024] @ [5120][1024]^T -> [4096][5120]
  gemm_bt<unsigned short><<<dim3(32,40), 256, 0, stream>>>(xb, WcatT, QKV, 4096, 5120, 1024);
  // V^T from QKV cols 4096..5119
  transpose_bf16_ld<<<dim3(32,128), tb, 0, stream>>>(QKV + 4096, Vtb, 4096, 1024, 5120);

  diff_attn<<<dim3(16,16,2), 256, 0, stream>>>(QKV, QKV + 2048, Vtb, lambp, AOb);

  gemm_bt<float><<<dim3(32,8), 256, 0, stream>>>(AOb, WoT, proj, 4096, 1024, 1024);
  ln_k<<<4096, 256, 0, stream>>>(proj, gamma, beta, out);
}

// Round 10
// 201.750 us; speedup vs baseline: 3.6000x; 1.1457x over previous
//
#include <hip/hip_runtime.h>
#include <hip/hip_bf16.h>

typedef short bf16x8 __attribute__((ext_vector_type(8)));
typedef float f32x4 __attribute__((ext_vector_type(4)));
typedef unsigned short us4v __attribute__((ext_vector_type(4)));
typedef unsigned int uint2v __attribute__((ext_vector_type(2)));

#define DEV static __device__ __forceinline__

DEV float bf2f(unsigned short u){ unsigned int x = ((unsigned int)u)<<16; float f; __builtin_memcpy(&f,&x,4); return f; }
DEV unsigned short f2bf(float f){ unsigned int x; __builtin_memcpy(&x,&f,4); x = (x + 0x7fffu + ((x>>16)&1u)) >> 16; return (unsigned short)x; }

// truncation pack: bf16(lo) | bf16(hi)<<16, round-toward-zero (3 VALU ops).
DEV unsigned int pack_trunc(float lo, float hi){
  unsigned int a, b;
  __builtin_memcpy(&a, &lo, 4);
  __builtin_memcpy(&b, &hi, 4);
  return (b & 0xffff0000u) | (a >> 16);
}

DEV void stor(unsigned short* p, float v){ *p = f2bf(v); }
DEV void stor(float* p, float v){ *p = v; }

#if __has_builtin(__builtin_amdgcn_exp2f)
DEV float fexp2(float x){ return __builtin_amdgcn_exp2f(x); }   // bare v_exp_f32; |x|<=~12 here
#else
DEV float fexp2(float x){ return exp2f(x); }
#endif

#if __has_builtin(__builtin_amdgcn_permlane32_swap)
DEV uint2v pl32(unsigned int a, unsigned int b){ return __builtin_amdgcn_permlane32_swap(a, b, false, false); }
#else
DEV uint2v pl32(unsigned int a, unsigned int b){
  unsigned int sa = (unsigned int)__shfl_xor((int)a, 32);
  unsigned int sb = (unsigned int)__shfl_xor((int)b, 32);
  bool hi = (threadIdx.x & 32) != 0;
  uint2v r; r[0] = hi ? sb : a; r[1] = hi ? b : sa; return r;
}
#endif
#if __has_builtin(__builtin_amdgcn_permlane16_swap)
DEV uint2v pl16(unsigned int a, unsigned int b){ return __builtin_amdgcn_permlane16_swap(a, b, false, false); }
#else
DEV uint2v pl16(unsigned int a, unsigned int b){
  unsigned int sa = (unsigned int)__shfl_xor((int)a, 16);
  unsigned int sb = (unsigned int)__shfl_xor((int)b, 16);
  bool hi = (threadIdx.x & 16) != 0;
  uint2v r; r[0] = hi ? sb : a; r[1] = hi ? b : sa; return r;
}
#endif

#define GLOAD_LDS16(gptr, lptr) \
  __builtin_amdgcn_global_load_lds((__attribute__((address_space(1))) void*)(gptr), \
      (__attribute__((address_space(3))) void*)(lptr), 16, 0, 0)

// C = A[M,K] @ Bt[N,K]^T, bf16 inputs, OutT output. 128x128 tile, BK=32, 4 waves.
template<typename OutT>
__global__ __launch_bounds__(256) void gemm_bt(
    const unsigned short* __restrict__ A,
    const unsigned short* __restrict__ Bt,
    OutT* __restrict__ C, int M, int N, int K)
{
  __shared__ unsigned short As[128*32];
  __shared__ unsigned short Bs[128*32];
  const int tid = threadIdx.x;
  const int w = tid>>6, l = tid&63, g = l>>4, q = l&15;
  const int m0 = blockIdx.x*128, n0 = blockIdx.y*128;
  f32x4 acc[4][4];
  const f32x4 fz = {0.f,0.f,0.f,0.f};
  for (int i=0;i<4;i++) for(int j=0;j<4;j++) acc[i][j] = fz;
  for (int k0 = 0; k0 < K; k0 += 32) {
    __syncthreads();
    #pragma unroll
    for (int r = 0; r < 2; ++r) {
      int p = r*4096 + tid*16;
      int row = p>>6, colb = p&63;
      const char* ga = (const char*)(A  + (size_t)(m0+row)*K + k0) + colb;
      const char* gb = (const char*)(Bt + (size_t)(n0+row)*K + k0) + colb;
      GLOAD_LDS16(ga, (char*)As + r*4096 + w*1024);
      GLOAD_LDS16(gb, (char*)Bs + r*4096 + w*1024);
    }
    __syncthreads();
    bf16x8 af[4], bfr[4];
    #pragma unroll
    for (int i=0;i<4;i++){
      af[i]  = *(const bf16x8*)&As[((w>>1)*64 + i*16 + q)*32 + g*8];
      bfr[i] = *(const bf16x8*)&Bs[((w&1)*64 + i*16 + q)*32 + g*8];
    }
    #pragma unroll
    for (int i=0;i<4;i++)
      #pragma unroll
      for (int j=0;j<4;j++)
        acc[i][j] = __builtin_amdgcn_mfma_f32_16x16x32_bf16(af[i], bfr[j], acc[i][j], 0,0,0);
  }
  #pragma unroll
  for (int i=0;i<4;i++)
    #pragma unroll
    for (int j=0;j<4;j++)
      #pragma unroll
      for (int v=0;v<4;v++){
        int row = m0 + (w>>1)*64 + i*16 + g*4 + v;
        int col = n0 + (w&1)*64 + j*16 + q;
        stor(&C[(size_t)row*N + col], acc[i][j][v]);
      }
}

// Differential flash attention v10: v9 structure with (a) staging via
// global_load_lds + pre-swizzled source (no reg roundtrip, no ds_writes),
// (b) bare v_exp_f32, (c) Q pre-scaled in the weights (no prologue rescale).
// Qp/Kp rows ld=5120 (merged QKV); Vt: [1024][4096]. aout: [4096][1024].
__global__ __launch_bounds__(256,2) void diff_attn(
    const unsigned short* __restrict__ Qp,
    const unsigned short* __restrict__ Kp,
    const unsigned short* __restrict__ Vt,
    const float* __restrict__ lambp,
    unsigned short* __restrict__ aout)
{
  const int LDQ = 5120;
  __shared__ unsigned short Ks[2][64*128];   // 32 KiB, granule ^ (row&7)
  __shared__ unsigned short Vs[2][64*64];    // 16 KiB, granule ^ (row&7) [d-major]
  const int tid = threadIdx.x, w = tid>>6, l = tid&63, g = l>>4, q = l&15;
  const int qb = blockIdx.x, h = blockIdx.y, b = blockIdx.z;
  const int b2048 = b*2048;
  const int qrow0 = b2048 + qb*128 + w*32;
  const f32x4 fz = {0.f,0.f,0.f,0.f};
  const short one_bf = (short)0x3f80;
  const bf16x8 ones = {one_bf,one_bf,one_bf,one_bf,one_bf,one_bf,one_bf,one_bf};

  // Q fragments for 2 q-subtiles (already scaled by 0.125*log2e via Wq)
  bf16x8 q1f[2][2], q2f[2][2];
  #pragma unroll
  for (int qh=0; qh<2; ++qh){
    const unsigned short* qp = Qp + (size_t)(qrow0 + qh*16 + q)*LDQ + h*128;
    #pragma unroll
    for (int kf=0;kf<2;kf++){
      q1f[qh][kf] = *(const bf16x8*)(qp + kf*32 + g*8);
      q2f[qh][kf] = *(const bf16x8*)(qp + 64 + kf*32 + g*8);
    }
  }
  f32x4 acc1[2][4], acc2[2][4];
  f32x4 acc_s1[2], acc_s2[2];   // denominators via P @ ones
  #pragma unroll
  for (int qh=0;qh<2;qh++){
    acc_s1[qh]=fz; acc_s2[qh]=fz;
    #pragma unroll
    for (int i=0;i<4;i++){ acc1[qh][i]=fz; acc2[qh][i]=fz; }
  }

  // async staging: linear LDS dest (base + lane*16), inverse-swizzled global src
  auto STAGE = [&](int bb, int kt){
    #pragma unroll
    for (int ii=0; ii<4; ++ii){
      int krow = w*16 + ii*4 + (l>>4);
      int gr = (l&15) ^ (krow&7);
      const unsigned short* src = Kp + (size_t)(b2048 + kt + krow)*LDQ + h*128 + gr*8;
      GLOAD_LDS16(src, (char*)&Ks[bb][0] + (w*16 + ii*4)*256);
    }
    #pragma unroll
    for (int jj=0; jj<2; ++jj){
      int vrow = w*16 + jj*8 + (l>>3);
      int gr = (l&7) ^ (vrow&7);
      const unsigned short* src = Vt + (size_t)(h*64 + vrow)*4096 + b2048 + kt + gr*8;
      GLOAD_LDS16(src, (char*)&Vs[bb][0] + (w*16 + jj*8)*128);
    }
  };

  STAGE(0, 0);
  __syncthreads();   // implicit vmcnt(0) drain: tile 0 landed

  for (int t=0; t<32; ++t) {
    const int bb = t & 1;
    if (t < 31) STAGE(bb^1, (t+1)*64);   // async into other buffer
    const int sw = q & 7;

    // ---- swapped QK^T: per qh, z[fn] = C[key=fn*16+g*4+i][qrow] ----
    unsigned int c1[2][4][2], c2[2][4][2];
    #pragma unroll
    for (int fn=0; fn<4; ++fn) {
      const unsigned short* kr = &Ks[bb][(fn*16 + q)*128];
      bf16x8 kb0 = *(const bf16x8*)&kr[((0+g)^sw)*8];
      bf16x8 kb1 = *(const bf16x8*)&kr[((4+g)^sw)*8];
      bf16x8 kc0 = *(const bf16x8*)&kr[((8+g)^sw)*8];
      bf16x8 kc1 = *(const bf16x8*)&kr[((12+g)^sw)*8];
      f32x4 za[2], zc[2];
      __builtin_amdgcn_s_setprio(1);
      #pragma unroll
      for (int qh=0; qh<2; ++qh){
        f32x4 a = fz, c = fz;
        a = __builtin_amdgcn_mfma_f32_16x16x32_bf16(kb0, q1f[qh][0], a, 0,0,0);
        a = __builtin_amdgcn_mfma_f32_16x16x32_bf16(kb1, q1f[qh][1], a, 0,0,0);
        c = __builtin_amdgcn_mfma_f32_16x16x32_bf16(kc0, q2f[qh][0], c, 0,0,0);
        c = __builtin_amdgcn_mfma_f32_16x16x32_bf16(kc1, q2f[qh][1], c, 0,0,0);
        za[qh]=a; zc[qh]=c;
      }
      __builtin_amdgcn_s_setprio(0);
      #pragma unroll
      for (int qh=0; qh<2; ++qh){
        float e0 = fexp2(za[qh][0]), e1 = fexp2(za[qh][1]);
        float e2 = fexp2(za[qh][2]), e3 = fexp2(za[qh][3]);
        c1[qh][fn][0] = pack_trunc(e0,e1); c1[qh][fn][1] = pack_trunc(e2,e3);
        float f0 = fexp2(zc[qh][0]), f1 = fexp2(zc[qh][1]);
        float f2 = fexp2(zc[qh][2]), f3 = fexp2(zc[qh][3]);
        c2[qh][fn][0] = pack_trunc(f0,f1); c2[qh][fn][1] = pack_trunc(f2,f3);
      }
    }

    // ---- in-register P -> A-frag via permlane swaps (per qh) ----
    bf16x8 pa1[2][2], pa2[2][2];
    #pragma unroll
    for (int qh=0; qh<2; ++qh)
      #pragma unroll
      for (int kh=0; kh<2; ++kh){
        unsigned int* u1 = (unsigned int*)&pa1[qh][kh];
        unsigned int* u2 = (unsigned int*)&pa2[qh][kh];
        #pragma unroll
        for (int j=0;j<2;j++){
          uint2v d = pl32(c1[qh][2*kh][j], c1[qh][2*kh+1][j]);
          uint2v e = pl16(d[0], d[1]);
          u1[j] = e[0]; u1[2+j] = e[1];
          uint2v d2 = pl32(c2[qh][2*kh][j], c2[qh][2*kh+1][j]);
          uint2v e2 = pl16(d2[0], d2[1]);
          u2[j] = e2[0]; u2[2+j] = e2[1];
        }
      }

    // ---- PV + denominator MFMAs ----
    __builtin_amdgcn_s_setprio(1);
    #pragma unroll
    for (int kh=0; kh<2; ++kh){
      #pragma unroll
      for (int qh=0; qh<2; ++qh){
        acc_s1[qh] = __builtin_amdgcn_mfma_f32_16x16x32_bf16(pa1[qh][kh], ones, acc_s1[qh], 0,0,0);
        acc_s2[qh] = __builtin_amdgcn_mfma_f32_16x16x32_bf16(pa2[qh][kh], ones, acc_s2[qh], 0,0,0);
      }
      #pragma unroll
      for (int fd=0; fd<4; ++fd){
        bf16x8 vb = *(const bf16x8*)&Vs[bb][(fd*16+q)*64 + ((kh*4+g)^sw)*8];
        #pragma unroll
        for (int qh=0; qh<2; ++qh){
          acc1[qh][fd] = __builtin_amdgcn_mfma_f32_16x16x32_bf16(pa1[qh][kh], vb, acc1[qh][fd], 0,0,0);
          acc2[qh][fd] = __builtin_amdgcn_mfma_f32_16x16x32_bf16(pa2[qh][kh], vb, acc2[qh][fd], 0,0,0);
        }
      }
    }
    __builtin_amdgcn_s_setprio(0);

    if (t < 31) __syncthreads();   // reads done + staged tile landed (vmcnt drain)
  }

  // epilogue: acc_s[i] = s[qrow=g*4+i] (all lanes), layout-aligned with acc1
  float lamb = lambp[0];
  #pragma unroll
  for (int qh=0; qh<2; ++qh){
    float inv1[4], inv2[4];
    #pragma unroll
    for (int i=0;i<4;i++){
      inv1[i] = 1.0f/acc_s1[qh][i];
      inv2[i] = lamb/acc_s2[qh][i];
    }
    #pragma unroll
    for (int fd=0; fd<4; ++fd)
      #pragma unroll
      for (int i=0;i<4;i++){
        float val = acc1[qh][fd][i]*inv1[i] - acc2[qh][fd][i]*inv2[i];
        int row = qrow0 + qh*16 + g*4 + i;
        int col = h*64 + fd*16 + q;
        aout[(size_t)row*1024 + col] = f2bf(val);
      }
  }
}

__global__ __launch_bounds__(256) void f32_to_bf16_k(const float* __restrict__ in, unsigned short* __restrict__ out, int n){
  int i = (blockIdx.x*256 + threadIdx.x)*4;
  if (i >= n) return;
  float4 vv = *(const float4*)(in + i);
  us4v o; o[0]=f2bf(vv.x); o[1]=f2bf(vv.y); o[2]=f2bf(vv.z); o[3]=f2bf(vv.w);
  *(us4v*)(out + i) = o;
}

// in: [R][C] f32 -> out: [C][R] bf16, values scaled by `scale`
__global__ void transpose_f32_bf16(const float* __restrict__ in, unsigned short* __restrict__ out, int R, int C, float scale){
  __shared__ unsigned short t[32][33];
  int c0 = blockIdx.x*32, r0 = blockIdx.y*32;
  int x = threadIdx.x, y = threadIdx.y;
  #pragma unroll
  for (int d=0; d<32; d+=8) t[y+d][x] = f2bf(in[(size_t)(r0+y+d)*C + c0 + x] * scale);
  __syncthreads();
  #pragma unroll
  for (int d=0; d<32; d+=8) out[(size_t)(c0+y+d)*R + r0 + x] = t[x][y+d];
}

// in: [R][C] bf16 (row stride ldin) -> out: [C][R] bf16
__global__ void transpose_bf16_ld(const unsigned short* __restrict__ in, unsigned short* __restrict__ out, int R, int C, int ldin){
  __shared__ unsigned short t[32][33];
  int c0 = blockIdx.x*32, r0 = blockIdx.y*32;
  int x = threadIdx.x, y = threadIdx.y;
  #pragma unroll
  for (int d=0; d<32; d+=8) t[y+d][x] = in[(size_t)(r0+y+d)*ldin + c0 + x];
  __syncthreads();
  #pragma unroll
  for (int d=0; d<32; d+=8) out[(size_t)(c0+y+d)*R + r0 + x] = t[x][y+d];
}

__global__ void lamb_k(const float* lq1, const float* lk1, const float* lq2, const float* lk2, float* out){
  int i = threadIdx.x;
  float a = lq1[i]*lk1[i], c = lq2[i]*lk2[i];
  #pragma unroll
  for (int o=32;o>0;o>>=1){ a += __shfl_down(a,o); c += __shfl_down(c,o); }
  if (i==0) out[0] = expf(a) - expf(c) + 0.7778700995592560f; // LAMBDA_INIT for layer 12
}

__global__ __launch_bounds__(256) void ln_k(const float* __restrict__ in, const float* __restrict__ gam,
                                            const float* __restrict__ bet, float* __restrict__ out){
  int row = blockIdx.x, t = threadIdx.x;
  const float4* rp = (const float4*)(in + (size_t)row*1024);
  float4 v4 = rp[t];
  float s = v4.x+v4.y+v4.z+v4.w;
  float ss = v4.x*v4.x+v4.y*v4.y+v4.z*v4.z+v4.w*v4.w;
  #pragma unroll
  for (int o=1;o<64;o<<=1){ s += __shfl_xor(s,o); ss += __shfl_xor(ss,o); }
  __shared__ float red[8];
  int w = t>>6, l = t&63;
  if (l==0){ red[w]=s; red[4+w]=ss; }
  __syncthreads();
  s = red[0]+red[1]+red[2]+red[3];
  ss = red[4]+red[5]+red[6]+red[7];
  float mean = s*(1.0f/1024.0f);
  float var = ss*(1.0f/1024.0f) - mean*mean;
  float rstd = rsqrtf(var + 1e-5f);
  float4 gv = ((const float4*)gam)[t], bv = ((const float4*)bet)[t];
  float4 o;
  o.x = (v4.x-mean)*rstd*gv.x + bv.x;
  o.y = (v4.y-mean)*rstd*gv.y + bv.y;
  o.z = (v4.z-mean)*rstd*gv.z + bv.z;
  o.w = (v4.w-mean)*rstd*gv.w + bv.w;
  ((float4*)(out + (size_t)row*1024))[t] = o;
}

extern "C" void kernel_launch(void* const* d_in, const int* in_sizes, int n_in,
                              void* d_out, int out_size, void* d_ws, size_t ws_size,
                              hipStream_t stream) {
  const float* x     = (const float*)d_in[0];
  const float* Wq    = (const float*)d_in[1];
  const float* Wk    = (const float*)d_in[2];
  const float* Wv    = (const float*)d_in[3];
  const float* Wo    = (const float*)d_in[4];
  const float* lq1   = (const float*)d_in[5];
  const float* lk1   = (const float*)d_in[6];
  const float* lq2   = (const float*)d_in[7];
  const float* lk2   = (const float*)d_in[8];
  const float* gamma = (const float*)d_in[9];
  const float* beta  = (const float*)d_in[10];
  float* out = (float*)d_out;

  char* ws = (char*)d_ws;
  unsigned short* xb    = (unsigned short*)(ws);                   //  8,388,608 B
  unsigned short* WcatT = (unsigned short*)(ws + 8388608);         // 10,485,760  [5120][1024]
  unsigned short* WoT   = (unsigned short*)(ws + 18874368);        //  2,097,152
  unsigned short* QKV   = (unsigned short*)(ws + 20971520);        // 41,943,040  [4096][5120]
  unsigned short* Vtb   = (unsigned short*)(ws + 62914560);        //  8,388,608  [1024][4096]
  unsigned short* AOb   = (unsigned short*)(ws + 71303168);        //  8,388,608
  float*          proj  = (float*)(ws + 79691776);                 // 16,777,216
  float*          lambp = (float*)(ws + 96468992);                 //  4

  const float QSCALE = 0.125f * 1.4426950408889634f;  // folded into Wq
  dim3 tb(32,8);
  f32_to_bf16_k<<<4096, 256, 0, stream>>>(x, xb, 4194304);
  transpose_f32_bf16<<<dim3(64,32), tb, 0, stream>>>(Wq, WcatT,             1024, 2048, QSCALE);
  transpose_f32_bf16<<<dim3(64,32), tb, 0, stream>>>(Wk, WcatT + 2048*1024, 1024, 2048, 1.0f);
  transpose_f32_bf16<<<dim3(32,32), tb, 0, stream>>>(Wv, WcatT + 4096*1024, 1024, 1024, 1.0f);
  transpose_f32_bf16<<<dim3(32,32), tb, 0, stream>>>(Wo, WoT, 1024, 1024, 1.0f);
  lamb_k<<<1, 64, 0, stream>>>(lq1, lk1, lq2, lk2, lambp);

  // fused QKV projection: [4096][1024] @ [5120][1024]^T -> [4096][5120]
  gemm_bt<unsigned short><<<dim3(32,40), 256, 0, stream>>>(xb, WcatT, QKV, 4096, 5120, 1024);
  // V^T from QKV cols 4096..5119
  transpose_bf16_ld<<<dim3(32,128), tb, 0, stream>>>(QKV + 4096, Vtb, 4096, 1024, 5120);

  diff_attn<<<dim3(16,16,2), 256, 0, stream>>>(QKV, QKV + 2048, Vtb, lambp, AOb);

  gemm_bt<float><<<dim3(32,8), 256, 0, stream>>>(AOb, WoT, proj, 4096, 1024, 1024);
  ln_k<<<4096, 256, 0, stream>>>(proj, gamma, beta, out);
}